// Round 1
// baseline (979.015 us; speedup 1.0000x reference)
//
#include <hip/hip_runtime.h>
#include <math.h>

#define AGENTS 400
#define BATCH  64
#define IDIM   50
#define HDIM   192
#define ODIM   3
#define ADIMM  128
#define NHEADS 8
#define HEADD  16
#define LN_EPS 1e-5f

__device__ __forceinline__ float gelu_exact(float x) {
    return 0.5f * x * (1.0f + erff(x * 0.70710678118654752f));
}

// ---------------------------------------------------------------------------
// Kernel A: per-agent MLP.  One block (256 thr) per agent.
// x[B,I] -> LN(shared stats, per-agent affine) -> h1 -> h2 -> h3 (LN) -> global
// Thread tiling for GEMMs: cx = tid&63 owns cols {cx, cx+64, cx+128},
// ry = tid>>6 owns rows [ry*16, ry*16+16).  LDS reads broadcast per wave.
// ---------------------------------------------------------------------------
__global__ __launch_bounds__(256) void mlp_kernel(
    const float* __restrict__ x,
    const float* __restrict__ ln_in_g, const float* __restrict__ ln_in_b,
    const float* __restrict__ W1, const float* __restrict__ b1,
    const float* __restrict__ Ws1, const float* __restrict__ bs1,
    const float* __restrict__ W2, const float* __restrict__ b2,
    const float* __restrict__ Ws2, const float* __restrict__ bs2,
    const float* __restrict__ W3, const float* __restrict__ b3,
    const float* __restrict__ ln_h_g, const float* __restrict__ ln_h_b,
    float* __restrict__ h3out)
{
    const int a   = blockIdx.x;
    const int tid = threadIdx.x;

    __shared__ float xs[BATCH][IDIM + 1];
    __shared__ float h1s[BATCH][HDIM + 1];
    __shared__ float h2s[BATCH][HDIM + 1];
    __shared__ float mu_s[BATCH], rs_s[BATCH];

    // load x, per-row stats (stats use raw x only; affine is per-agent)
    for (int idx = tid; idx < BATCH * IDIM; idx += 256) {
        int r = idx / IDIM, c = idx - r * IDIM;
        xs[r][c] = x[idx];
    }
    __syncthreads();
    if (tid < BATCH) {
        float s = 0.f, ss = 0.f;
        for (int i = 0; i < IDIM; i++) { float v = xs[tid][i]; s += v; ss += v * v; }
        float mu = s * (1.0f / IDIM);
        float var = ss * (1.0f / IDIM) - mu * mu;
        mu_s[tid] = mu;
        rs_s[tid] = rsqrtf(var + LN_EPS);
    }
    __syncthreads();
    for (int idx = tid; idx < BATCH * IDIM; idx += 256) {
        int r = idx / IDIM, c = idx - r * IDIM;
        xs[r][c] = (xs[r][c] - mu_s[r]) * rs_s[r] * ln_in_g[a * IDIM + c] + ln_in_b[a * IDIM + c];
    }
    __syncthreads();

    const int cx = tid & 63;
    const int r0 = (tid >> 6) * 16;

    // ---- h1 = gelu(xn*W1 + b1) + xn*Ws1 + bs1 ----
    {
        float acc1[3][16], acc2[3][16];
        #pragma unroll
        for (int m = 0; m < 3; m++)
            #pragma unroll
            for (int r = 0; r < 16; r++) { acc1[m][r] = 0.f; acc2[m][r] = 0.f; }
        const float* W1p  = W1  + (size_t)a * IDIM * HDIM;
        const float* Ws1p = Ws1 + (size_t)a * IDIM * HDIM;
        for (int k = 0; k < IDIM; k++) {
            float w[3], ws[3];
            #pragma unroll
            for (int m = 0; m < 3; m++) {
                w[m]  = W1p[k * HDIM + cx + 64 * m];
                ws[m] = Ws1p[k * HDIM + cx + 64 * m];
            }
            #pragma unroll
            for (int r = 0; r < 16; r++) {
                float xv = xs[r0 + r][k];
                #pragma unroll
                for (int m = 0; m < 3; m++) {
                    acc1[m][r] = fmaf(xv, w[m],  acc1[m][r]);
                    acc2[m][r] = fmaf(xv, ws[m], acc2[m][r]);
                }
            }
        }
        #pragma unroll
        for (int m = 0; m < 3; m++) {
            int c = cx + 64 * m;
            float bb  = b1[a * HDIM + c];
            float bbs = bs1[a * HDIM + c];
            #pragma unroll
            for (int r = 0; r < 16; r++)
                h1s[r0 + r][c] = gelu_exact(acc1[m][r] + bb) + acc2[m][r] + bbs;
        }
    }
    __syncthreads();

    // ---- h2 = gelu(h1*W2 + b2) + h1*Ws2 + bs2 ----
    {
        float acc1[3][16], acc2[3][16];
        #pragma unroll
        for (int m = 0; m < 3; m++)
            #pragma unroll
            for (int r = 0; r < 16; r++) { acc1[m][r] = 0.f; acc2[m][r] = 0.f; }
        const float* W2p  = W2  + (size_t)a * HDIM * HDIM;
        const float* Ws2p = Ws2 + (size_t)a * HDIM * HDIM;
        for (int k = 0; k < HDIM; k++) {
            float w[3], ws[3];
            #pragma unroll
            for (int m = 0; m < 3; m++) {
                w[m]  = W2p[k * HDIM + cx + 64 * m];
                ws[m] = Ws2p[k * HDIM + cx + 64 * m];
            }
            #pragma unroll
            for (int r = 0; r < 16; r++) {
                float hv = h1s[r0 + r][k];
                #pragma unroll
                for (int m = 0; m < 3; m++) {
                    acc1[m][r] = fmaf(hv, w[m],  acc1[m][r]);
                    acc2[m][r] = fmaf(hv, ws[m], acc2[m][r]);
                }
            }
        }
        #pragma unroll
        for (int m = 0; m < 3; m++) {
            int c = cx + 64 * m;
            float bb  = b2[a * HDIM + c];
            float bbs = bs2[a * HDIM + c];
            #pragma unroll
            for (int r = 0; r < 16; r++)
                h2s[r0 + r][c] = gelu_exact(acc1[m][r] + bb) + acc2[m][r] + bbs;
        }
    }
    __syncthreads();

    // ---- t = h2 + h2*W3 + b3 -> LN (per-agent affine) -> h3out ----
    {
        float acc[3][16];
        #pragma unroll
        for (int m = 0; m < 3; m++)
            #pragma unroll
            for (int r = 0; r < 16; r++) acc[m][r] = 0.f;
        const float* W3p = W3 + (size_t)a * HDIM * HDIM;
        for (int k = 0; k < HDIM; k++) {
            float w[3];
            #pragma unroll
            for (int m = 0; m < 3; m++) w[m] = W3p[k * HDIM + cx + 64 * m];
            #pragma unroll
            for (int r = 0; r < 16; r++) {
                float hv = h2s[r0 + r][k];
                #pragma unroll
                for (int m = 0; m < 3; m++) acc[m][r] = fmaf(hv, w[m], acc[m][r]);
            }
        }
        #pragma unroll
        for (int m = 0; m < 3; m++) {
            int c = cx + 64 * m;
            float bb = b3[a * HDIM + c];
            #pragma unroll
            for (int r = 0; r < 16; r++)
                h1s[r0 + r][c] = h2s[r0 + r][c] + acc[m][r] + bb;   // reuse h1s as t
        }
    }
    __syncthreads();
    if (tid < BATCH) {
        float s = 0.f, ss = 0.f;
        for (int i = 0; i < HDIM; i++) { float v = h1s[tid][i]; s += v; ss += v * v; }
        float mu = s * (1.0f / HDIM);
        float var = ss * (1.0f / HDIM) - mu * mu;
        mu_s[tid] = mu;
        rs_s[tid] = rsqrtf(var + LN_EPS);
    }
    __syncthreads();
    for (int idx = tid; idx < BATCH * HDIM; idx += 256) {
        int r = idx / HDIM, c = idx - r * HDIM;
        float v = (h1s[r][c] - mu_s[r]) * rs_s[r] * ln_h_g[a * HDIM + c] + ln_h_b[a * HDIM + c];
        h3out[((size_t)a * BATCH + r) * HDIM + c] = v;
    }
}

// ---------------------------------------------------------------------------
// Kernel B: y = LN(h3, shared affine); q/k/v = y*W{q,k,v} + b, written
// transposed to [b, h, a, d] so attention reads contiguous chunks.
// One block per agent.
// ---------------------------------------------------------------------------
__global__ __launch_bounds__(256) void qkv_kernel(
    const float* __restrict__ h3,
    const float* __restrict__ aln_g, const float* __restrict__ aln_b,
    const float* __restrict__ Wq, const float* __restrict__ bq,
    const float* __restrict__ Wk, const float* __restrict__ bk,
    const float* __restrict__ Wv, const float* __restrict__ bv,
    float* __restrict__ qT, float* __restrict__ kT, float* __restrict__ vT)
{
    const int a   = blockIdx.x;
    const int tid = threadIdx.x;
    __shared__ float ys[BATCH][HDIM + 1];
    __shared__ float mu_s[BATCH], rs_s[BATCH];

    for (int idx = tid; idx < BATCH * HDIM; idx += 256) {
        int r = idx / HDIM, c = idx - r * HDIM;
        ys[r][c] = h3[((size_t)a * BATCH + r) * HDIM + c];
    }
    __syncthreads();
    if (tid < BATCH) {
        float s = 0.f, ss = 0.f;
        for (int i = 0; i < HDIM; i++) { float v = ys[tid][i]; s += v; ss += v * v; }
        float mu = s * (1.0f / HDIM);
        float var = ss * (1.0f / HDIM) - mu * mu;
        mu_s[tid] = mu;
        rs_s[tid] = rsqrtf(var + LN_EPS);
    }
    __syncthreads();
    for (int idx = tid; idx < BATCH * HDIM; idx += 256) {
        int r = idx / HDIM, c = idx - r * HDIM;
        ys[r][c] = (ys[r][c] - mu_s[r]) * rs_s[r] * aln_g[c] + aln_b[c];
    }
    __syncthreads();

    const int cx = tid & 63;
    const int r0 = (tid >> 6) * 16;
    float acc[6][16];
    #pragma unroll
    for (int m = 0; m < 6; m++)
        #pragma unroll
        for (int r = 0; r < 16; r++) acc[m][r] = 0.f;

    for (int k = 0; k < HDIM; k++) {
        float w[6];
        w[0] = Wq[k * ADIMM + cx];      w[1] = Wq[k * ADIMM + cx + 64];
        w[2] = Wk[k * ADIMM + cx];      w[3] = Wk[k * ADIMM + cx + 64];
        w[4] = Wv[k * ADIMM + cx];      w[5] = Wv[k * ADIMM + cx + 64];
        #pragma unroll
        for (int r = 0; r < 16; r++) {
            float yv = ys[r0 + r][k];
            #pragma unroll
            for (int m = 0; m < 6; m++) acc[m][r] = fmaf(yv, w[m], acc[m][r]);
        }
    }

    #pragma unroll
    for (int m = 0; m < 2; m++) {
        int c = cx + 64 * m, h = c >> 4, d = c & 15;
        float bb = bq[c];
        #pragma unroll
        for (int r = 0; r < 16; r++) {
            int b = r0 + r;
            qT[(((size_t)b * NHEADS + h) * AGENTS + a) * HEADD + d] = acc[m][r] + bb;
        }
    }
    #pragma unroll
    for (int m = 0; m < 2; m++) {
        int c = cx + 64 * m, h = c >> 4, d = c & 15;
        float bb = bk[c];
        #pragma unroll
        for (int r = 0; r < 16; r++) {
            int b = r0 + r;
            kT[(((size_t)b * NHEADS + h) * AGENTS + a) * HEADD + d] = acc[2 + m][r] + bb;
        }
    }
    #pragma unroll
    for (int m = 0; m < 2; m++) {
        int c = cx + 64 * m, h = c >> 4, d = c & 15;
        float bb = bv[c];
        #pragma unroll
        for (int r = 0; r < 16; r++) {
            int b = r0 + r;
            vT[(((size_t)b * NHEADS + h) * AGENTS + a) * HEADD + d] = acc[4 + m][r] + bb;
        }
    }
}

// ---------------------------------------------------------------------------
// Kernel C: cross-agent attention.  grid = 512 (b,h) * 2 row-halves.
// K,V for the (b,h) instance staged in LDS; each thread owns one query row,
// online-softmax accumulation.
// ---------------------------------------------------------------------------
__global__ __launch_bounds__(256) void attn_kernel(
    const float* __restrict__ qT, const float* __restrict__ kT,
    const float* __restrict__ vT, float* __restrict__ oT)
{
    const int bh   = blockIdx.x >> 1;
    const int half = blockIdx.x & 1;
    const int tid  = threadIdx.x;

    __shared__ float ks[AGENTS * HEADD];
    __shared__ float vs[AGENTS * HEADD];
    const float* kp = kT + (size_t)bh * AGENTS * HEADD;
    const float* vp = vT + (size_t)bh * AGENTS * HEADD;
    for (int i = tid; i < AGENTS * HEADD; i += 256) { ks[i] = kp[i]; vs[i] = vp[i]; }
    __syncthreads();

    const int row = half * 200 + tid;    // 200 rows per half-block
    if (tid < 200 && row < AGENTS) {
        float q[16];
        const float* qp = qT + ((size_t)bh * AGENTS + row) * HEADD;
        #pragma unroll
        for (int d = 0; d < 16; d++) q[d] = qp[d];

        float m = -1e30f, l = 0.f;
        float o[16];
        #pragma unroll
        for (int d = 0; d < 16; d++) o[d] = 0.f;

        for (int c = 0; c < AGENTS; c++) {
            const float* kk = &ks[c * HEADD];
            float s = 0.f;
            #pragma unroll
            for (int d = 0; d < 16; d++) s = fmaf(q[d], kk[d], s);
            s *= 0.25f;   // SCALE = HD^-0.5
            if (s > m) {
                float corr = __expf(m - s);
                l *= corr;
                #pragma unroll
                for (int d = 0; d < 16; d++) o[d] *= corr;
                m = s;
            }
            float p = __expf(s - m);
            l += p;
            const float* vv = &vs[c * HEADD];
            #pragma unroll
            for (int d = 0; d < 16; d++) o[d] = fmaf(p, vv[d], o[d]);
        }
        float inv = 1.0f / l;
        float* op = oT + ((size_t)bh * AGENTS + row) * HEADD;
        #pragma unroll
        for (int d = 0; d < 16; d++) op[d] = o[d] * inv;
    }
}

// ---------------------------------------------------------------------------
// Kernel D: attended = h3 + o*Wo + bo;  logits = attended*Wout[a] + bout[a].
// One block per agent.
// ---------------------------------------------------------------------------
__global__ __launch_bounds__(256) void out_kernel(
    const float* __restrict__ h3, const float* __restrict__ oT,
    const float* __restrict__ Wo, const float* __restrict__ bo,
    const float* __restrict__ Wout, const float* __restrict__ bout,
    float* __restrict__ out)
{
    const int a   = blockIdx.x;
    const int tid = threadIdx.x;
    __shared__ float os[BATCH][ADIMM + 1];
    __shared__ float att[BATCH][HDIM + 1];

    for (int idx = tid; idx < BATCH * HDIM; idx += 256) {
        int r = idx / HDIM, c = idx - r * HDIM;
        att[r][c] = h3[((size_t)a * BATCH + r) * HDIM + c];
    }
    for (int idx = tid; idx < BATCH * ADIMM; idx += 256) {
        int b = idx >> 7, j = idx & 127;
        int h = j >> 4, d = j & 15;
        os[b][j] = oT[(((size_t)b * NHEADS + h) * AGENTS + a) * HEADD + d];
    }
    __syncthreads();

    const int cx = tid & 63;
    const int r0 = (tid >> 6) * 16;
    {
        float acc[3][16];
        #pragma unroll
        for (int m = 0; m < 3; m++)
            #pragma unroll
            for (int r = 0; r < 16; r++) acc[m][r] = 0.f;
        for (int k = 0; k < ADIMM; k++) {
            float w[3];
            #pragma unroll
            for (int m = 0; m < 3; m++) w[m] = Wo[k * HDIM + cx + 64 * m];
            #pragma unroll
            for (int r = 0; r < 16; r++) {
                float ov = os[r0 + r][k];
                #pragma unroll
                for (int m = 0; m < 3; m++) acc[m][r] = fmaf(ov, w[m], acc[m][r]);
            }
        }
        #pragma unroll
        for (int m = 0; m < 3; m++) {
            int c = cx + 64 * m;
            float bb = bo[c];
            #pragma unroll
            for (int r = 0; r < 16; r++)
                att[r0 + r][c] += acc[m][r] + bb;
        }
    }
    __syncthreads();

    if (tid < BATCH * ODIM) {
        int r = tid % BATCH;       // lanes vary over r -> conflict-free LDS
        int c = tid / BATCH;       // 0..2
        const float* Wp = Wout + (size_t)a * HDIM * ODIM;
        float accv = 0.f;
        for (int k = 0; k < HDIM; k++)
            accv = fmaf(att[r][k], Wp[k * ODIM + c], accv);
        out[((size_t)a * BATCH + r) * ODIM + c] = accv + bout[a * ODIM + c];
    }
}

// ---------------------------------------------------------------------------
extern "C" void kernel_launch(void* const* d_in, const int* in_sizes, int n_in,
                              void* d_out, int out_size, void* d_ws, size_t ws_size,
                              hipStream_t stream)
{
    const float* x       = (const float*)d_in[0];
    const float* ln_in_g = (const float*)d_in[1];
    const float* ln_in_b = (const float*)d_in[2];
    const float* W1      = (const float*)d_in[3];
    const float* b1      = (const float*)d_in[4];
    const float* Ws1     = (const float*)d_in[5];
    const float* bs1     = (const float*)d_in[6];
    const float* W2      = (const float*)d_in[7];
    const float* b2      = (const float*)d_in[8];
    const float* Ws2     = (const float*)d_in[9];
    const float* bs2     = (const float*)d_in[10];
    const float* W3      = (const float*)d_in[11];
    const float* b3      = (const float*)d_in[12];
    const float* ln_h_g  = (const float*)d_in[13];
    const float* ln_h_b  = (const float*)d_in[14];
    const float* Wout    = (const float*)d_in[15];
    const float* bout    = (const float*)d_in[16];
    const float* aln_g   = (const float*)d_in[17];
    const float* aln_b   = (const float*)d_in[18];
    const float* Wq      = (const float*)d_in[19];
    const float* bq      = (const float*)d_in[20];
    const float* Wk      = (const float*)d_in[21];
    const float* bk      = (const float*)d_in[22];
    const float* Wv      = (const float*)d_in[23];
    const float* bv      = (const float*)d_in[24];
    const float* Wo      = (const float*)d_in[25];
    const float* bo      = (const float*)d_in[26];
    float* out = (float*)d_out;

    float* ws = (float*)d_ws;
    const size_t H3_SZ = (size_t)AGENTS * BATCH * HDIM;              // 4,915,200
    const size_t QT_SZ = (size_t)BATCH * NHEADS * AGENTS * HEADD;    // 3,276,800
    float* h3 = ws;
    float* qT = h3 + H3_SZ;
    float* kT = qT + QT_SZ;
    float* vT = kT + QT_SZ;
    float* oT = vT + QT_SZ;

    mlp_kernel<<<AGENTS, 256, 0, stream>>>(x, ln_in_g, ln_in_b,
                                           W1, b1, Ws1, bs1, W2, b2, Ws2, bs2,
                                           W3, b3, ln_h_g, ln_h_b, h3);
    qkv_kernel<<<AGENTS, 256, 0, stream>>>(h3, aln_g, aln_b,
                                           Wq, bq, Wk, bk, Wv, bv, qT, kT, vT);
    attn_kernel<<<BATCH * NHEADS * 2, 256, 0, stream>>>(qT, kT, vT, oT);
    out_kernel<<<AGENTS, 256, 0, stream>>>(h3, oT, Wo, bo, Wout, bout, out);
}

// Round 2
// 609.537 us; speedup vs baseline: 1.6062x; 1.6062x over previous
//
#include <hip/hip_runtime.h>
#include <math.h>

#define AGENTS 400
#define BATCH  64
#define IDIM   50
#define HDIM   192
#define ODIM   3
#define ADIMM  128
#define NHEADS 8
#define HEADD  16
#define LN_EPS 1e-5f

__device__ __forceinline__ float gelu_exact(float x) {
    return 0.5f * x * (1.0f + erff(x * 0.70710678118654752f));
}

// ---------------------------------------------------------------------------
// Kernel A: per-agent MLP, 4-way batch-row split.
// grid = (AGENTS, 4); block 256.  Each block: rows [by*16, by*16+16).
// LDS ~28 KB -> 5 blocks/CU (20 waves/CU) for latency hiding.
// GEMM tiling: cx = tid&63 owns cols {cx,cx+64,cx+128}; rowgrp = tid>>6 owns
// 4 rows.  Weight loads are coalesced 256B/wave; activations broadcast from
// LDS.
// ---------------------------------------------------------------------------
__global__ __launch_bounds__(256) void mlp_kernel(
    const float* __restrict__ x,
    const float* __restrict__ ln_in_g, const float* __restrict__ ln_in_b,
    const float* __restrict__ W1, const float* __restrict__ b1,
    const float* __restrict__ Ws1, const float* __restrict__ bs1,
    const float* __restrict__ W2, const float* __restrict__ b2,
    const float* __restrict__ Ws2, const float* __restrict__ bs2,
    const float* __restrict__ W3, const float* __restrict__ b3,
    const float* __restrict__ ln_h_g, const float* __restrict__ ln_h_b,
    float* __restrict__ h3out)
{
    const int a      = blockIdx.x;
    const int r_base = blockIdx.y * 16;
    const int tid    = threadIdx.x;

    __shared__ float xs[16][IDIM + 1];
    __shared__ float h1s[16][HDIM + 1];
    __shared__ float h2s[16][HDIM + 1];
    __shared__ float mu_s[16], rs_s[16];

    // load x rows (x is [B,I], shared across agents)
    for (int idx = tid; idx < 16 * IDIM; idx += 256) {
        int r = idx / IDIM, c = idx - r * IDIM;
        xs[r][c] = x[(r_base + r) * IDIM + c];
    }
    __syncthreads();
    // per-row stats: 16 lanes per row, shfl reduce
    {
        int r = tid >> 4, l = tid & 15;
        float s = 0.f, ss = 0.f;
        for (int k = l; k < IDIM; k += 16) { float v = xs[r][k]; s += v; ss += v * v; }
        #pragma unroll
        for (int off = 8; off; off >>= 1) {
            s  += __shfl_down(s,  off, 16);
            ss += __shfl_down(ss, off, 16);
        }
        if (l == 0) {
            float mu = s * (1.0f / IDIM);
            float var = ss * (1.0f / IDIM) - mu * mu;
            mu_s[r] = mu;
            rs_s[r] = rsqrtf(var + LN_EPS);
        }
    }
    __syncthreads();
    for (int idx = tid; idx < 16 * IDIM; idx += 256) {
        int r = idx / IDIM, c = idx - r * IDIM;
        xs[r][c] = (xs[r][c] - mu_s[r]) * rs_s[r] * ln_in_g[a * IDIM + c] + ln_in_b[a * IDIM + c];
    }
    __syncthreads();

    const int cx = tid & 63;
    const int rg = (tid >> 6) * 4;

    // ---- h1 = gelu(xn*W1 + b1) + xn*Ws1 + bs1 ----
    {
        float acc1[3][4], acc2[3][4];
        #pragma unroll
        for (int m = 0; m < 3; m++)
            #pragma unroll
            for (int r = 0; r < 4; r++) { acc1[m][r] = 0.f; acc2[m][r] = 0.f; }
        const float* W1p  = W1  + (size_t)a * IDIM * HDIM;
        const float* Ws1p = Ws1 + (size_t)a * IDIM * HDIM;
        for (int k = 0; k < IDIM; k++) {
            float w[3], ws[3];
            #pragma unroll
            for (int m = 0; m < 3; m++) {
                w[m]  = W1p[k * HDIM + cx + 64 * m];
                ws[m] = Ws1p[k * HDIM + cx + 64 * m];
            }
            #pragma unroll
            for (int r = 0; r < 4; r++) {
                float xv = xs[rg + r][k];
                #pragma unroll
                for (int m = 0; m < 3; m++) {
                    acc1[m][r] = fmaf(xv, w[m],  acc1[m][r]);
                    acc2[m][r] = fmaf(xv, ws[m], acc2[m][r]);
                }
            }
        }
        #pragma unroll
        for (int m = 0; m < 3; m++) {
            int c = cx + 64 * m;
            float bb  = b1[a * HDIM + c];
            float bbs = bs1[a * HDIM + c];
            #pragma unroll
            for (int r = 0; r < 4; r++)
                h1s[rg + r][c] = gelu_exact(acc1[m][r] + bb) + acc2[m][r] + bbs;
        }
    }
    __syncthreads();

    // ---- h2 = gelu(h1*W2 + b2) + h1*Ws2 + bs2 ----
    {
        float acc1[3][4], acc2[3][4];
        #pragma unroll
        for (int m = 0; m < 3; m++)
            #pragma unroll
            for (int r = 0; r < 4; r++) { acc1[m][r] = 0.f; acc2[m][r] = 0.f; }
        const float* W2p  = W2  + (size_t)a * HDIM * HDIM;
        const float* Ws2p = Ws2 + (size_t)a * HDIM * HDIM;
        for (int k = 0; k < HDIM; k++) {
            float w[3], ws[3];
            #pragma unroll
            for (int m = 0; m < 3; m++) {
                w[m]  = W2p[k * HDIM + cx + 64 * m];
                ws[m] = Ws2p[k * HDIM + cx + 64 * m];
            }
            #pragma unroll
            for (int r = 0; r < 4; r++) {
                float hv = h1s[rg + r][k];
                #pragma unroll
                for (int m = 0; m < 3; m++) {
                    acc1[m][r] = fmaf(hv, w[m],  acc1[m][r]);
                    acc2[m][r] = fmaf(hv, ws[m], acc2[m][r]);
                }
            }
        }
        #pragma unroll
        for (int m = 0; m < 3; m++) {
            int c = cx + 64 * m;
            float bb  = b2[a * HDIM + c];
            float bbs = bs2[a * HDIM + c];
            #pragma unroll
            for (int r = 0; r < 4; r++)
                h2s[rg + r][c] = gelu_exact(acc1[m][r] + bb) + acc2[m][r] + bbs;
        }
    }
    __syncthreads();

    // ---- t = h2 + h2*W3 + b3 -> LN -> h3out ----
    {
        float acc[3][4];
        #pragma unroll
        for (int m = 0; m < 3; m++)
            #pragma unroll
            for (int r = 0; r < 4; r++) acc[m][r] = 0.f;
        const float* W3p = W3 + (size_t)a * HDIM * HDIM;
        for (int k = 0; k < HDIM; k++) {
            float w[3];
            #pragma unroll
            for (int m = 0; m < 3; m++) w[m] = W3p[k * HDIM + cx + 64 * m];
            #pragma unroll
            for (int r = 0; r < 4; r++) {
                float hv = h2s[rg + r][k];
                #pragma unroll
                for (int m = 0; m < 3; m++) acc[m][r] = fmaf(hv, w[m], acc[m][r]);
            }
        }
        #pragma unroll
        for (int m = 0; m < 3; m++) {
            int c = cx + 64 * m;
            float bb = b3[a * HDIM + c];
            #pragma unroll
            for (int r = 0; r < 4; r++)
                h1s[rg + r][c] = h2s[rg + r][c] + acc[m][r] + bb;   // t in h1s
        }
    }
    __syncthreads();
    {
        int r = tid >> 4, l = tid & 15;
        float s = 0.f, ss = 0.f;
        for (int k = l; k < HDIM; k += 16) { float v = h1s[r][k]; s += v; ss += v * v; }
        #pragma unroll
        for (int off = 8; off; off >>= 1) {
            s  += __shfl_down(s,  off, 16);
            ss += __shfl_down(ss, off, 16);
        }
        if (l == 0) {
            float mu = s * (1.0f / HDIM);
            float var = ss * (1.0f / HDIM) - mu * mu;
            mu_s[r] = mu;
            rs_s[r] = rsqrtf(var + LN_EPS);
        }
    }
    __syncthreads();
    for (int idx = tid; idx < 16 * HDIM; idx += 256) {
        int r = idx / HDIM, c = idx - r * HDIM;
        float v = (h1s[r][c] - mu_s[r]) * rs_s[r] * ln_h_g[a * HDIM + c] + ln_h_b[a * HDIM + c];
        h3out[((size_t)a * BATCH + (r_base + r)) * HDIM + c] = v;
    }
}

// ---------------------------------------------------------------------------
// Kernel B: y = LN(h3, shared affine); q/k/v GEMMs, 2-way batch-row split.
// grid = (AGENTS, 2); block 256; rows [by*32, by*32+32).  LDS ~25 KB.
// ---------------------------------------------------------------------------
__global__ __launch_bounds__(256) void qkv_kernel(
    const float* __restrict__ h3,
    const float* __restrict__ aln_g, const float* __restrict__ aln_b,
    const float* __restrict__ Wq, const float* __restrict__ bq,
    const float* __restrict__ Wk, const float* __restrict__ bk,
    const float* __restrict__ Wv, const float* __restrict__ bv,
    float* __restrict__ qT, float* __restrict__ kT, float* __restrict__ vT)
{
    const int a      = blockIdx.x;
    const int r_base = blockIdx.y * 32;
    const int tid    = threadIdx.x;
    __shared__ float ys[32][HDIM + 1];
    __shared__ float mu_s[32], rs_s[32];

    for (int idx = tid; idx < 32 * HDIM; idx += 256) {
        int r = idx / HDIM, c = idx - r * HDIM;
        ys[r][c] = h3[((size_t)a * BATCH + (r_base + r)) * HDIM + c];
    }
    __syncthreads();
    {
        int r = tid >> 3, l = tid & 7;
        float s = 0.f, ss = 0.f;
        for (int k = l; k < HDIM; k += 8) { float v = ys[r][k]; s += v; ss += v * v; }
        #pragma unroll
        for (int off = 4; off; off >>= 1) {
            s  += __shfl_down(s,  off, 8);
            ss += __shfl_down(ss, off, 8);
        }
        if (l == 0) {
            float mu = s * (1.0f / HDIM);
            float var = ss * (1.0f / HDIM) - mu * mu;
            mu_s[r] = mu;
            rs_s[r] = rsqrtf(var + LN_EPS);
        }
    }
    __syncthreads();
    for (int idx = tid; idx < 32 * HDIM; idx += 256) {
        int r = idx / HDIM, c = idx - r * HDIM;
        ys[r][c] = (ys[r][c] - mu_s[r]) * rs_s[r] * aln_g[c] + aln_b[c];
    }
    __syncthreads();

    const int cx = tid & 63;
    const int rg = (tid >> 6) * 8;
    float acc[6][8];
    #pragma unroll
    for (int m = 0; m < 6; m++)
        #pragma unroll
        for (int r = 0; r < 8; r++) acc[m][r] = 0.f;

    for (int k = 0; k < HDIM; k++) {
        float w[6];
        w[0] = Wq[k * ADIMM + cx];      w[1] = Wq[k * ADIMM + cx + 64];
        w[2] = Wk[k * ADIMM + cx];      w[3] = Wk[k * ADIMM + cx + 64];
        w[4] = Wv[k * ADIMM + cx];      w[5] = Wv[k * ADIMM + cx + 64];
        #pragma unroll
        for (int r = 0; r < 8; r++) {
            float yv = ys[rg + r][k];
            #pragma unroll
            for (int m = 0; m < 6; m++) acc[m][r] = fmaf(yv, w[m], acc[m][r]);
        }
    }

    #pragma unroll
    for (int m = 0; m < 2; m++) {
        int c = cx + 64 * m, h = c >> 4, d = c & 15;
        float bbq = bq[c], bbk = bk[c], bbv = bv[c];
        #pragma unroll
        for (int r = 0; r < 8; r++) {
            int b = r_base + rg + r;
            size_t base = (((size_t)b * NHEADS + h) * AGENTS + a) * HEADD + d;
            qT[base] = acc[m][r]     + bbq;
            kT[base] = acc[2 + m][r] + bbk;
            vT[base] = acc[4 + m][r] + bbv;
        }
    }
}

// ---------------------------------------------------------------------------
// Kernel C: cross-agent attention.  grid = 512 (b,h); block 512 (8 waves).
// K,V staged in LDS (50 KB -> 3 blocks/CU); thread t owns query row t.
// ---------------------------------------------------------------------------
__global__ __launch_bounds__(512) void attn_kernel(
    const float* __restrict__ qT, const float* __restrict__ kT,
    const float* __restrict__ vT, float* __restrict__ oT)
{
    const int bh  = blockIdx.x;
    const int tid = threadIdx.x;

    __shared__ float ks[AGENTS * HEADD];
    __shared__ float vs[AGENTS * HEADD];
    const float4* kp = (const float4*)(kT + (size_t)bh * AGENTS * HEADD);
    const float4* vp = (const float4*)(vT + (size_t)bh * AGENTS * HEADD);
    for (int i = tid; i < AGENTS * HEADD / 4; i += 512) {
        ((float4*)ks)[i] = kp[i];
        ((float4*)vs)[i] = vp[i];
    }
    __syncthreads();

    if (tid < AGENTS) {
        float q[16];
        const float* qp = qT + ((size_t)bh * AGENTS + tid) * HEADD;
        #pragma unroll
        for (int d = 0; d < 16; d++) q[d] = qp[d];

        float m = -1e30f, l = 0.f;
        float o[16];
        #pragma unroll
        for (int d = 0; d < 16; d++) o[d] = 0.f;

        for (int c = 0; c < AGENTS; c++) {
            const float* kk = &ks[c * HEADD];
            float s = 0.f;
            #pragma unroll
            for (int d = 0; d < 16; d++) s = fmaf(q[d], kk[d], s);
            s *= 0.25f;   // SCALE = HD^-0.5
            if (s > m) {
                float corr = __expf(m - s);
                l *= corr;
                #pragma unroll
                for (int d = 0; d < 16; d++) o[d] *= corr;
                m = s;
            }
            float p = __expf(s - m);
            l += p;
            const float* vv = &vs[c * HEADD];
            #pragma unroll
            for (int d = 0; d < 16; d++) o[d] = fmaf(p, vv[d], o[d]);
        }
        float inv = 1.0f / l;
        float* op = oT + ((size_t)bh * AGENTS + tid) * HEADD;
        #pragma unroll
        for (int d = 0; d < 16; d++) op[d] = o[d] * inv;
    }
}

// ---------------------------------------------------------------------------
// Kernel D: attended = h3 + o*Wo + bo; logits = attended*Wout[a] + bout[a].
// grid = (AGENTS, 2); block 256; rows [by*32, by*32+32).  LDS ~41 KB.
// ---------------------------------------------------------------------------
__global__ __launch_bounds__(256) void out_kernel(
    const float* __restrict__ h3, const float* __restrict__ oT,
    const float* __restrict__ Wo, const float* __restrict__ bo,
    const float* __restrict__ Wout, const float* __restrict__ bout,
    float* __restrict__ out)
{
    const int a      = blockIdx.x;
    const int r_base = blockIdx.y * 32;
    const int tid    = threadIdx.x;
    __shared__ float os[32][ADIMM + 1];
    __shared__ float att[32][HDIM + 1];

    for (int idx = tid; idx < 32 * HDIM; idx += 256) {
        int r = idx / HDIM, c = idx - r * HDIM;
        att[r][c] = h3[((size_t)a * BATCH + (r_base + r)) * HDIM + c];
    }
    for (int idx = tid; idx < 32 * ADIMM; idx += 256) {
        int r = idx >> 7, j = idx & 127;
        int h = j >> 4, d = j & 15;
        int b = r_base + r;
        os[r][j] = oT[(((size_t)b * NHEADS + h) * AGENTS + a) * HEADD + d];
    }
    __syncthreads();

    const int cx = tid & 63;
    const int rg = (tid >> 6) * 8;
    {
        float acc[3][8];
        #pragma unroll
        for (int m = 0; m < 3; m++)
            #pragma unroll
            for (int r = 0; r < 8; r++) acc[m][r] = 0.f;
        for (int k = 0; k < ADIMM; k++) {
            float w[3];
            #pragma unroll
            for (int m = 0; m < 3; m++) w[m] = Wo[k * HDIM + cx + 64 * m];
            #pragma unroll
            for (int r = 0; r < 8; r++) {
                float ov = os[rg + r][k];
                #pragma unroll
                for (int m = 0; m < 3; m++) acc[m][r] = fmaf(ov, w[m], acc[m][r]);
            }
        }
        #pragma unroll
        for (int m = 0; m < 3; m++) {
            int c = cx + 64 * m;
            float bb = bo[c];
            #pragma unroll
            for (int r = 0; r < 8; r++)
                att[rg + r][c] += acc[m][r] + bb;
        }
    }
    __syncthreads();

    if (tid < 32 * ODIM) {
        int r = tid & 31;
        int c = tid >> 5;        // 0..2
        const float* Wp = Wout + (size_t)a * HDIM * ODIM;
        float accv = 0.f;
        for (int k = 0; k < HDIM; k++)
            accv = fmaf(att[r][k], Wp[k * ODIM + c], accv);
        out[((size_t)a * BATCH + (r_base + r)) * ODIM + c] = accv + bout[a * ODIM + c];
    }
}

// ---------------------------------------------------------------------------
extern "C" void kernel_launch(void* const* d_in, const int* in_sizes, int n_in,
                              void* d_out, int out_size, void* d_ws, size_t ws_size,
                              hipStream_t stream)
{
    const float* x       = (const float*)d_in[0];
    const float* ln_in_g = (const float*)d_in[1];
    const float* ln_in_b = (const float*)d_in[2];
    const float* W1      = (const float*)d_in[3];
    const float* b1      = (const float*)d_in[4];
    const float* Ws1     = (const float*)d_in[5];
    const float* bs1     = (const float*)d_in[6];
    const float* W2      = (const float*)d_in[7];
    const float* b2      = (const float*)d_in[8];
    const float* Ws2     = (const float*)d_in[9];
    const float* bs2     = (const float*)d_in[10];
    const float* W3      = (const float*)d_in[11];
    const float* b3      = (const float*)d_in[12];
    const float* ln_h_g  = (const float*)d_in[13];
    const float* ln_h_b  = (const float*)d_in[14];
    const float* Wout    = (const float*)d_in[15];
    const float* bout    = (const float*)d_in[16];
    const float* aln_g   = (const float*)d_in[17];
    const float* aln_b   = (const float*)d_in[18];
    const float* Wq      = (const float*)d_in[19];
    const float* bq      = (const float*)d_in[20];
    const float* Wk      = (const float*)d_in[21];
    const float* bk      = (const float*)d_in[22];
    const float* Wv      = (const float*)d_in[23];
    const float* bv      = (const float*)d_in[24];
    const float* Wo      = (const float*)d_in[25];
    const float* bo      = (const float*)d_in[26];
    float* out = (float*)d_out;

    float* ws = (float*)d_ws;
    const size_t H3_SZ = (size_t)AGENTS * BATCH * HDIM;              // 4,915,200
    const size_t QT_SZ = (size_t)BATCH * NHEADS * AGENTS * HEADD;    // 3,276,800
    float* h3 = ws;
    float* qT = h3 + H3_SZ;
    float* kT = qT + QT_SZ;
    float* vT = kT + QT_SZ;
    float* oT = vT + QT_SZ;

    mlp_kernel<<<dim3(AGENTS, 4), 256, 0, stream>>>(x, ln_in_g, ln_in_b,
                                                    W1, b1, Ws1, bs1, W2, b2, Ws2, bs2,
                                                    W3, b3, ln_h_g, ln_h_b, h3);
    qkv_kernel<<<dim3(AGENTS, 2), 256, 0, stream>>>(h3, aln_g, aln_b,
                                                    Wq, bq, Wk, bk, Wv, bv, qT, kT, vT);
    attn_kernel<<<BATCH * NHEADS, 512, 0, stream>>>(qT, kT, vT, oT);
    out_kernel<<<dim3(AGENTS, 2), 256, 0, stream>>>(h3, oT, Wo, bo, Wout, bout, out);
}

// Round 3
// 601.596 us; speedup vs baseline: 1.6274x; 1.0132x over previous
//
#include <hip/hip_runtime.h>
#include <math.h>

#define AGENTS 400
#define BATCH  64
#define IDIM   50
#define HDIM   192
#define ODIM   3
#define ADIMM  128
#define NHEADS 8
#define HEADD  16
#define LN_EPS 1e-5f

#define PA 200   // As pitch in bf16 (400 B rows: 16B-aligned, conflict-floor)
#define PWB 40   // Wt pitch in bf16 (80 B rows: 16B-aligned)

typedef __bf16 bf16x8 __attribute__((ext_vector_type(8)));
typedef float  f32x4  __attribute__((ext_vector_type(4)));

__device__ __forceinline__ float gelu_exact(float x) {
    return 0.5f * x * (1.0f + erff(x * 0.70710678118654752f));
}

// stage one K=32 chunk of W[kd x 192] into Wt[n][k] (bf16, transposed),
// zero-filling k >= kd.  Coalesced global reads; packed b32 LDS writes.
__device__ __forceinline__ void stage_w(__bf16* Wt, const float* __restrict__ Wg,
                                        int kc, int kd, int wave, int lane)
{
    #pragma unroll
    for (int i = 0; i < 4; i++) {
        int kp = (i << 2) + wave;            // 0..15  (k-pair slot)
        int k0 = kc + (kp << 1);
        #pragma unroll
        for (int j = 0; j < 3; j++) {
            int n = lane + (j << 6);         // 0..191
            float f0 = (k0     < kd) ? Wg[(size_t)k0 * HDIM + n]       : 0.f;
            float f1 = (k0 + 1 < kd) ? Wg[(size_t)(k0 + 1) * HDIM + n] : 0.f;
            unsigned short u0 = __builtin_bit_cast(unsigned short, (__bf16)f0);
            unsigned short u1 = __builtin_bit_cast(unsigned short, (__bf16)f1);
            *(unsigned int*)&Wt[n * PWB + (kp << 1)] =
                (unsigned int)u0 | ((unsigned int)u1 << 16);
        }
    }
}

__device__ __forceinline__ void mfma_tiles(f32x4* acc, const bf16x8 af,
                                           const __bf16* Wt, int lane)
{
    #pragma unroll
    for (int t = 0; t < 12; t++) {
        const bf16x8 bf = *(const bf16x8*)&Wt[((lane & 15) + (t << 4)) * PWB + ((lane >> 4) << 3)];
        acc[t] = __builtin_amdgcn_mfma_f32_16x16x32_bf16(af, bf, acc[t], 0, 0, 0);
    }
}

// ---------------------------------------------------------------------------
// Kernel A: per-agent MLP on MFMA.  One block (4 waves) per agent; weights
// fetched once (HBM-bound: ~208 MB fp32 across the grid).
// Wave w owns output rows [16w,16w+16): A-frag reads, epilogue writes, and
// residual reads are all wave-private -> barriers only around Wt staging.
// ---------------------------------------------------------------------------
__global__ __launch_bounds__(256, 3) void mlp_kernel(
    const float* __restrict__ x,
    const float* __restrict__ ln_in_g, const float* __restrict__ ln_in_b,
    const float* __restrict__ W1, const float* __restrict__ b1,
    const float* __restrict__ Ws1, const float* __restrict__ bs1,
    const float* __restrict__ W2, const float* __restrict__ b2,
    const float* __restrict__ Ws2, const float* __restrict__ bs2,
    const float* __restrict__ W3, const float* __restrict__ b3,
    const float* __restrict__ ln_h_g, const float* __restrict__ ln_h_b,
    float* __restrict__ h3out)
{
    const int a    = blockIdx.x;
    const int tid  = threadIdx.x;
    const int wave = tid >> 6, lane = tid & 63;

    __shared__ __align__(16) __bf16 As[64 * PA];      // 25.6 KB
    __shared__ __align__(16) __bf16 Wt[192 * PWB];    // 15.36 KB
    __shared__ float mu_s[64], rs_s[64];

    // ---- input LN: stats over raw x rows (shared), per-agent affine ----
    {
        int r = tid >> 2, l = tid & 3;
        float s = 0.f, ss = 0.f;
        for (int k = l; k < IDIM; k += 4) { float v = x[r * IDIM + k]; s += v; ss += v * v; }
        s  += __shfl_down(s, 2, 4);  s  += __shfl_down(s, 1, 4);
        ss += __shfl_down(ss, 2, 4); ss += __shfl_down(ss, 1, 4);
        if (l == 0) {
            float mu = s * (1.0f / IDIM);
            float var = ss * (1.0f / IDIM) - mu * mu;
            mu_s[r] = mu;
            rs_s[r] = rsqrtf(var + LN_EPS);
        }
    }
    __syncthreads();
    for (int sidx = tid; sidx < 64 * 64; sidx += 256) {
        int r = sidx >> 6, k = sidx & 63;
        float v = 0.f;
        if (k < IDIM)
            v = (x[r * IDIM + k] - mu_s[r]) * rs_s[r] * ln_in_g[a * IDIM + k] + ln_in_b[a * IDIM + k];
        As[r * PA + k] = (__bf16)v;   // zero-pad k in [IDIM,64)
    }

    const int arow = 16 * wave + (lane & 15);
    const int koff = (lane >> 4) << 3;
    const int rb   = 16 * wave + ((lane >> 4) << 2);

    // ================= stage 1: h1 = gelu(xn*W1+b1) + xn*Ws1+bs1 ==========
    {
        f32x4 acc1[12], acc2[12];
        #pragma unroll
        for (int t = 0; t < 12; t++) { acc1[t] = (f32x4)0.f; acc2[t] = (f32x4)0.f; }
        const float* W1p  = W1  + (size_t)a * IDIM * HDIM;
        const float* Ws1p = Ws1 + (size_t)a * IDIM * HDIM;
        for (int c = 0; c < 2; c++) {
            __syncthreads();
            stage_w(Wt, W1p, c * 32, IDIM, wave, lane);
            __syncthreads();
            bf16x8 af = *(const bf16x8*)&As[arow * PA + c * 32 + koff];
            mfma_tiles(acc1, af, Wt, lane);
            __syncthreads();
            stage_w(Wt, Ws1p, c * 32, IDIM, wave, lane);
            __syncthreads();
            mfma_tiles(acc2, af, Wt, lane);
        }
        #pragma unroll
        for (int t = 0; t < 12; t++) {
            int n = (lane & 15) + (t << 4);
            float bb  = b1[a * HDIM + n];
            float bbs = bs1[a * HDIM + n];
            #pragma unroll
            for (int g = 0; g < 4; g++) {
                float v = gelu_exact(acc1[t][g] + bb) + acc2[t][g] + bbs;
                As[(rb + g) * PA + n] = (__bf16)v;
            }
        }
    }

    // ================= stage 2: h2 = gelu(h1*W2+b2) + h1*Ws2+bs2 ==========
    {
        f32x4 acc1[12], acc2[12];
        #pragma unroll
        for (int t = 0; t < 12; t++) { acc1[t] = (f32x4)0.f; acc2[t] = (f32x4)0.f; }
        const float* W2p  = W2  + (size_t)a * HDIM * HDIM;
        const float* Ws2p = Ws2 + (size_t)a * HDIM * HDIM;
        for (int c = 0; c < 6; c++) {
            __syncthreads();
            stage_w(Wt, W2p, c * 32, HDIM, wave, lane);
            __syncthreads();
            bf16x8 af = *(const bf16x8*)&As[arow * PA + c * 32 + koff];
            mfma_tiles(acc1, af, Wt, lane);
            __syncthreads();
            stage_w(Wt, Ws2p, c * 32, HDIM, wave, lane);
            __syncthreads();
            mfma_tiles(acc2, af, Wt, lane);
        }
        #pragma unroll
        for (int t = 0; t < 12; t++) {
            int n = (lane & 15) + (t << 4);
            float bb  = b2[a * HDIM + n];
            float bbs = bs2[a * HDIM + n];
            #pragma unroll
            for (int g = 0; g < 4; g++) {
                float v = gelu_exact(acc1[t][g] + bb) + acc2[t][g] + bbs;
                As[(rb + g) * PA + n] = (__bf16)v;
            }
        }
    }

    // ================= stage 3: t = h2 + h2*W3 + b3, then LN ==============
    {
        f32x4 acc1[12];
        #pragma unroll
        for (int t = 0; t < 12; t++) acc1[t] = (f32x4)0.f;
        const float* W3p = W3 + (size_t)a * HDIM * HDIM;
        for (int c = 0; c < 6; c++) {
            __syncthreads();
            stage_w(Wt, W3p, c * 32, HDIM, wave, lane);
            __syncthreads();
            bf16x8 af = *(const bf16x8*)&As[arow * PA + c * 32 + koff];
            mfma_tiles(acc1, af, Wt, lane);
        }
        #pragma unroll
        for (int t = 0; t < 12; t++) {
            int n = (lane & 15) + (t << 4);
            float bb = b3[a * HDIM + n];
            #pragma unroll
            for (int g = 0; g < 4; g++) {
                int rr = rb + g;
                float v = (float)As[rr * PA + n] + acc1[t][g] + bb;
                As[rr * PA + n] = (__bf16)v;
            }
        }
    }
    __syncthreads();
    {
        int r = tid >> 2, l = tid & 3;
        float s = 0.f, ss = 0.f;
        for (int k = l; k < HDIM; k += 4) { float v = (float)As[r * PA + k]; s += v; ss += v * v; }
        s  += __shfl_down(s, 2, 4);  s  += __shfl_down(s, 1, 4);
        ss += __shfl_down(ss, 2, 4); ss += __shfl_down(ss, 1, 4);
        if (l == 0) {
            float mu = s * (1.0f / HDIM);
            float var = ss * (1.0f / HDIM) - mu * mu;
            mu_s[r] = mu;
            rs_s[r] = rsqrtf(var + LN_EPS);
        }
    }
    __syncthreads();
    for (int sidx = tid; sidx < 64 * HDIM; sidx += 256) {
        int r = sidx / HDIM, c = sidx - r * HDIM;
        float v = ((float)As[r * PA + c] - mu_s[r]) * rs_s[r] * ln_h_g[a * HDIM + c] + ln_h_b[a * HDIM + c];
        h3out[((size_t)a * BATCH + r) * HDIM + c] = v;
    }
}

// ---------------------------------------------------------------------------
// Kernel B: y = LN(h3, shared affine); q/k/v GEMMs, 2-way batch-row split.
// ---------------------------------------------------------------------------
__global__ __launch_bounds__(256) void qkv_kernel(
    const float* __restrict__ h3,
    const float* __restrict__ aln_g, const float* __restrict__ aln_b,
    const float* __restrict__ Wq, const float* __restrict__ bq,
    const float* __restrict__ Wk, const float* __restrict__ bk,
    const float* __restrict__ Wv, const float* __restrict__ bv,
    float* __restrict__ qT, float* __restrict__ kT, float* __restrict__ vT)
{
    const int a      = blockIdx.x;
    const int r_base = blockIdx.y * 32;
    const int tid    = threadIdx.x;
    __shared__ float ys[32][HDIM + 1];
    __shared__ float mu_s[32], rs_s[32];

    for (int idx = tid; idx < 32 * HDIM; idx += 256) {
        int r = idx / HDIM, c = idx - r * HDIM;
        ys[r][c] = h3[((size_t)a * BATCH + (r_base + r)) * HDIM + c];
    }
    __syncthreads();
    {
        int r = tid >> 3, l = tid & 7;
        float s = 0.f, ss = 0.f;
        for (int k = l; k < HDIM; k += 8) { float v = ys[r][k]; s += v; ss += v * v; }
        #pragma unroll
        for (int off = 4; off; off >>= 1) {
            s  += __shfl_down(s,  off, 8);
            ss += __shfl_down(ss, off, 8);
        }
        if (l == 0) {
            float mu = s * (1.0f / HDIM);
            float var = ss * (1.0f / HDIM) - mu * mu;
            mu_s[r] = mu;
            rs_s[r] = rsqrtf(var + LN_EPS);
        }
    }
    __syncthreads();
    for (int idx = tid; idx < 32 * HDIM; idx += 256) {
        int r = idx / HDIM, c = idx - r * HDIM;
        ys[r][c] = (ys[r][c] - mu_s[r]) * rs_s[r] * aln_g[c] + aln_b[c];
    }
    __syncthreads();

    const int cx = tid & 63;
    const int rg = (tid >> 6) * 8;
    float acc[6][8];
    #pragma unroll
    for (int m = 0; m < 6; m++)
        #pragma unroll
        for (int r = 0; r < 8; r++) acc[m][r] = 0.f;

    for (int k = 0; k < HDIM; k++) {
        float w[6];
        w[0] = Wq[k * ADIMM + cx];      w[1] = Wq[k * ADIMM + cx + 64];
        w[2] = Wk[k * ADIMM + cx];      w[3] = Wk[k * ADIMM + cx + 64];
        w[4] = Wv[k * ADIMM + cx];      w[5] = Wv[k * ADIMM + cx + 64];
        #pragma unroll
        for (int r = 0; r < 8; r++) {
            float yv = ys[rg + r][k];
            #pragma unroll
            for (int m = 0; m < 6; m++) acc[m][r] = fmaf(yv, w[m], acc[m][r]);
        }
    }

    #pragma unroll
    for (int m = 0; m < 2; m++) {
        int c = cx + 64 * m, h = c >> 4, d = c & 15;
        float bbq = bq[c], bbk = bk[c], bbv = bv[c];
        #pragma unroll
        for (int r = 0; r < 8; r++) {
            int b = r_base + rg + r;
            size_t base = (((size_t)b * NHEADS + h) * AGENTS + a) * HEADD + d;
            qT[base] = acc[m][r]     + bbq;
            kT[base] = acc[2 + m][r] + bbk;
            vT[base] = acc[4 + m][r] + bbv;
        }
    }
}

// ---------------------------------------------------------------------------
// Kernel C: cross-agent attention.  grid = 512 (b,h); block 512 (8 waves).
// ---------------------------------------------------------------------------
__global__ __launch_bounds__(512) void attn_kernel(
    const float* __restrict__ qT, const float* __restrict__ kT,
    const float* __restrict__ vT, float* __restrict__ oT)
{
    const int bh  = blockIdx.x;
    const int tid = threadIdx.x;

    __shared__ float ks[AGENTS * HEADD];
    __shared__ float vs[AGENTS * HEADD];
    const float4* kp = (const float4*)(kT + (size_t)bh * AGENTS * HEADD);
    const float4* vp = (const float4*)(vT + (size_t)bh * AGENTS * HEADD);
    for (int i = tid; i < AGENTS * HEADD / 4; i += 512) {
        ((float4*)ks)[i] = kp[i];
        ((float4*)vs)[i] = vp[i];
    }
    __syncthreads();

    if (tid < AGENTS) {
        float q[16];
        const float* qp = qT + ((size_t)bh * AGENTS + tid) * HEADD;
        #pragma unroll
        for (int d = 0; d < 16; d++) q[d] = qp[d];

        float m = -1e30f, l = 0.f;
        float o[16];
        #pragma unroll
        for (int d = 0; d < 16; d++) o[d] = 0.f;

        for (int c = 0; c < AGENTS; c++) {
            const float* kk = &ks[c * HEADD];
            float s = 0.f;
            #pragma unroll
            for (int d = 0; d < 16; d++) s = fmaf(q[d], kk[d], s);
            s *= 0.25f;   // SCALE = HD^-0.5
            if (s > m) {
                float corr = __expf(m - s);
                l *= corr;
                #pragma unroll
                for (int d = 0; d < 16; d++) o[d] *= corr;
                m = s;
            }
            float p = __expf(s - m);
            l += p;
            const float* vv = &vs[c * HEADD];
            #pragma unroll
            for (int d = 0; d < 16; d++) o[d] = fmaf(p, vv[d], o[d]);
        }
        float inv = 1.0f / l;
        float* op = oT + ((size_t)bh * AGENTS + tid) * HEADD;
        #pragma unroll
        for (int d = 0; d < 16; d++) op[d] = o[d] * inv;
    }
}

// ---------------------------------------------------------------------------
// Kernel D: attended = h3 + o*Wo + bo; logits = attended*Wout[a] + bout[a].
// ---------------------------------------------------------------------------
__global__ __launch_bounds__(256) void out_kernel(
    const float* __restrict__ h3, const float* __restrict__ oT,
    const float* __restrict__ Wo, const float* __restrict__ bo,
    const float* __restrict__ Wout, const float* __restrict__ bout,
    float* __restrict__ out)
{
    const int a      = blockIdx.x;
    const int r_base = blockIdx.y * 32;
    const int tid    = threadIdx.x;
    __shared__ float os[32][ADIMM + 1];
    __shared__ float att[32][HDIM + 1];

    for (int idx = tid; idx < 32 * HDIM; idx += 256) {
        int r = idx / HDIM, c = idx - r * HDIM;
        att[r][c] = h3[((size_t)a * BATCH + (r_base + r)) * HDIM + c];
    }
    for (int idx = tid; idx < 32 * ADIMM; idx += 256) {
        int r = idx >> 7, j = idx & 127;
        int h = j >> 4, d = j & 15;
        int b = r_base + r;
        os[r][j] = oT[(((size_t)b * NHEADS + h) * AGENTS + a) * HEADD + d];
    }
    __syncthreads();

    const int cx = tid & 63;
    const int rg = (tid >> 6) * 8;
    {
        float acc[3][8];
        #pragma unroll
        for (int m = 0; m < 3; m++)
            #pragma unroll
            for (int r = 0; r < 8; r++) acc[m][r] = 0.f;
        for (int k = 0; k < ADIMM; k++) {
            float w[3];
            #pragma unroll
            for (int m = 0; m < 3; m++) w[m] = Wo[k * HDIM + cx + 64 * m];
            #pragma unroll
            for (int r = 0; r < 8; r++) {
                float ov = os[rg + r][k];
                #pragma unroll
                for (int m = 0; m < 3; m++) acc[m][r] = fmaf(ov, w[m], acc[m][r]);
            }
        }
        #pragma unroll
        for (int m = 0; m < 3; m++) {
            int c = cx + 64 * m;
            float bb = bo[c];
            #pragma unroll
            for (int r = 0; r < 8; r++)
                att[rg + r][c] += acc[m][r] + bb;
        }
    }
    __syncthreads();

    if (tid < 32 * ODIM) {
        int r = tid & 31;
        int c = tid >> 5;        // 0..2
        const float* Wp = Wout + (size_t)a * HDIM * ODIM;
        float accv = 0.f;
        for (int k = 0; k < HDIM; k++)
            accv = fmaf(att[r][k], Wp[k * ODIM + c], accv);
        out[((size_t)a * BATCH + (r_base + r)) * ODIM + c] = accv + bout[a * ODIM + c];
    }
}

// ---------------------------------------------------------------------------
extern "C" void kernel_launch(void* const* d_in, const int* in_sizes, int n_in,
                              void* d_out, int out_size, void* d_ws, size_t ws_size,
                              hipStream_t stream)
{
    const float* x       = (const float*)d_in[0];
    const float* ln_in_g = (const float*)d_in[1];
    const float* ln_in_b = (const float*)d_in[2];
    const float* W1      = (const float*)d_in[3];
    const float* b1      = (const float*)d_in[4];
    const float* Ws1     = (const float*)d_in[5];
    const float* bs1     = (const float*)d_in[6];
    const float* W2      = (const float*)d_in[7];
    const float* b2      = (const float*)d_in[8];
    const float* Ws2     = (const float*)d_in[9];
    const float* bs2     = (const float*)d_in[10];
    const float* W3      = (const float*)d_in[11];
    const float* b3      = (const float*)d_in[12];
    const float* ln_h_g  = (const float*)d_in[13];
    const float* ln_h_b  = (const float*)d_in[14];
    const float* Wout    = (const float*)d_in[15];
    const float* bout    = (const float*)d_in[16];
    const float* aln_g   = (const float*)d_in[17];
    const float* aln_b   = (const float*)d_in[18];
    const float* Wq      = (const float*)d_in[19];
    const float* bq      = (const float*)d_in[20];
    const float* Wk      = (const float*)d_in[21];
    const float* bk      = (const float*)d_in[22];
    const float* Wv      = (const float*)d_in[23];
    const float* bv      = (const float*)d_in[24];
    const float* Wo      = (const float*)d_in[25];
    const float* bo      = (const float*)d_in[26];
    float* out = (float*)d_out;

    float* ws = (float*)d_ws;
    const size_t H3_SZ = (size_t)AGENTS * BATCH * HDIM;              // 4,915,200
    const size_t QT_SZ = (size_t)BATCH * NHEADS * AGENTS * HEADD;    // 3,276,800
    float* h3 = ws;
    float* qT = h3 + H3_SZ;
    float* kT = qT + QT_SZ;
    float* vT = kT + QT_SZ;
    float* oT = vT + QT_SZ;

    mlp_kernel<<<AGENTS, 256, 0, stream>>>(x, ln_in_g, ln_in_b,
                                           W1, b1, Ws1, bs1, W2, b2, Ws2, bs2,
                                           W3, b3, ln_h_g, ln_h_b, h3);
    qkv_kernel<<<dim3(AGENTS, 2), 256, 0, stream>>>(h3, aln_g, aln_b,
                                                    Wq, bq, Wk, bk, Wv, bv, qT, kT, vT);
    attn_kernel<<<BATCH * NHEADS, 512, 0, stream>>>(qT, kT, vT, oT);
    out_kernel<<<dim3(AGENTS, 2), 256, 0, stream>>>(h3, oT, Wo, bo, Wout, bout, out);
}

// Round 4
// 485.916 us; speedup vs baseline: 2.0148x; 1.2381x over previous
//
#include <hip/hip_runtime.h>
#include <math.h>

#define AGENTS 400
#define BATCH  64
#define IDIM   50
#define HDIM   192
#define ODIM   3
#define ADIMM  128
#define NHEADS 8
#define HEADD  16
#define LN_EPS 1e-5f

#define PA 200   // activation LDS pitch in bf16 (400 B rows, 16B-aligned)

typedef __bf16 bf16x8 __attribute__((ext_vector_type(8)));
typedef float  f32x4  __attribute__((ext_vector_type(4)));

__device__ __forceinline__ float gelu_exact(float x) {
    return 0.5f * x * (1.0f + erff(x * 0.70710678118654752f));
}

// ---------------------------------------------------------------------------
// Barrier-free GEMM pass over K (NC chunks of 32), B built straight from
// global fp32 into register fragments, double-buffered one chunk ahead.
// Wave owns NT 16-col tiles (wptr[t] = matrix base + col offset, row-major,
// leading dim LDW) and all 64 batch rows (4 row-groups).
//   B-frag: lane(g=lane>>4, r=lane&15) holds W[k=c*32+g*8+j][col_t + r]
//   A-frag: As[(16*rg + r)*PA + c*32 + g*8 .. +7]  (bf16)
// ---------------------------------------------------------------------------
template<int NC, int KD, int NT, int LDW>
__device__ __forceinline__ void gemm_bpass(f32x4 (&acc)[4][NT],
                                           const float* const* wptr,
                                           const __bf16* Asrc, int lane)
{
    const int r = lane & 15, g = lane >> 4;
    float buf[2][NT * 8];

    #pragma unroll
    for (int t = 0; t < NT; t++)
        #pragma unroll
        for (int j = 0; j < 8; j++) {
            int k = g * 8 + j;
            buf[0][t * 8 + j] = (k < KD) ? wptr[t][k * LDW + r] : 0.f;
        }

    #pragma unroll
    for (int c = 0; c < NC; c++) {
        const int cur = c & 1, nxt = cur ^ 1;
        if (c + 1 < NC) {
            #pragma unroll
            for (int t = 0; t < NT; t++)
                #pragma unroll
                for (int j = 0; j < 8; j++) {
                    int k = (c + 1) * 32 + g * 8 + j;
                    buf[nxt][t * 8 + j] = (k < KD) ? wptr[t][k * LDW + r] : 0.f;
                }
        }
        bf16x8 bfr[NT];
        #pragma unroll
        for (int t = 0; t < NT; t++)
            #pragma unroll
            for (int j = 0; j < 8; j++)
                bfr[t][j] = (__bf16)buf[cur][t * 8 + j];
        #pragma unroll
        for (int rg = 0; rg < 4; rg++) {
            bf16x8 af = *(const bf16x8*)&Asrc[(16 * rg + r) * PA + c * 32 + g * 8];
            #pragma unroll
            for (int t = 0; t < NT; t++)
                acc[rg][t] = __builtin_amdgcn_mfma_f32_16x16x32_bf16(af, bfr[t], acc[rg][t], 0, 0, 0);
        }
    }
}

// ---------------------------------------------------------------------------
// Kernel A: per-agent MLP on MFMA.  One block (4 waves) per agent.
// Wave w owns output cols [48w, 48w+48); barriers only around epilogues.
// ---------------------------------------------------------------------------
__global__ __launch_bounds__(256, 2) void mlp_kernel(
    const float* __restrict__ x,
    const float* __restrict__ ln_in_g, const float* __restrict__ ln_in_b,
    const float* __restrict__ W1, const float* __restrict__ b1,
    const float* __restrict__ Ws1, const float* __restrict__ bs1,
    const float* __restrict__ W2, const float* __restrict__ b2,
    const float* __restrict__ Ws2, const float* __restrict__ bs2,
    const float* __restrict__ W3, const float* __restrict__ b3,
    const float* __restrict__ ln_h_g, const float* __restrict__ ln_h_b,
    float* __restrict__ h3out)
{
    const int a    = blockIdx.x;
    const int tid  = threadIdx.x;
    const int wave = tid >> 6, lane = tid & 63;
    const int r = lane & 15, g = lane >> 4;
    const int n0 = 48 * wave;

    __shared__ __align__(16) __bf16 As[64 * PA];   // 25.6 KB
    __shared__ float mu_s[64], rs_s[64];

    // ---- input LN: stats on raw x rows (shared), per-agent affine ----
    {
        int rr = tid >> 2, l = tid & 3;
        float s = 0.f, ss = 0.f;
        for (int k = l; k < IDIM; k += 4) { float v = x[rr * IDIM + k]; s += v; ss += v * v; }
        s  += __shfl_down(s, 2, 4);  s  += __shfl_down(s, 1, 4);
        ss += __shfl_down(ss, 2, 4); ss += __shfl_down(ss, 1, 4);
        if (l == 0) {
            float mu = s * (1.0f / IDIM);
            float var = ss * (1.0f / IDIM) - mu * mu;
            mu_s[rr] = mu;
            rs_s[rr] = rsqrtf(var + LN_EPS);
        }
    }
    __syncthreads();
    for (int sidx = tid; sidx < 64 * 64; sidx += 256) {
        int rr = sidx >> 6, k = sidx & 63;
        float v = 0.f;
        if (k < IDIM)
            v = (x[rr * IDIM + k] - mu_s[rr]) * rs_s[rr] * ln_in_g[a * IDIM + k] + ln_in_b[a * IDIM + k];
        As[rr * PA + k] = (__bf16)v;   // zero-pad k in [IDIM,64)
    }
    __syncthreads();

    // ================= stage 1: h1 = gelu(xn*W1+b1) + xn*Ws1+bs1 ==========
    {
        f32x4 acc1[4][3], acc2[4][3];
        #pragma unroll
        for (int i = 0; i < 4; i++)
            #pragma unroll
            for (int t = 0; t < 3; t++) { acc1[i][t] = (f32x4)0.f; acc2[i][t] = (f32x4)0.f; }
        const float* W1p  = W1  + (size_t)a * IDIM * HDIM;
        const float* Ws1p = Ws1 + (size_t)a * IDIM * HDIM;
        const float* wA[3] = { W1p + n0,  W1p + n0 + 16,  W1p + n0 + 32 };
        const float* wB[3] = { Ws1p + n0, Ws1p + n0 + 16, Ws1p + n0 + 32 };
        gemm_bpass<2, IDIM, 3, HDIM>(acc1, wA, As, lane);
        gemm_bpass<2, IDIM, 3, HDIM>(acc2, wB, As, lane);
        __syncthreads();
        #pragma unroll
        for (int t = 0; t < 3; t++) {
            int col = n0 + 16 * t + r;
            float bb  = b1[a * HDIM + col];
            float bbs = bs1[a * HDIM + col];
            #pragma unroll
            for (int rg = 0; rg < 4; rg++)
                #pragma unroll
                for (int i = 0; i < 4; i++) {
                    int row = 16 * rg + 4 * g + i;
                    float v = gelu_exact(acc1[rg][t][i] + bb) + acc2[rg][t][i] + bbs;
                    As[row * PA + col] = (__bf16)v;
                }
        }
        __syncthreads();
    }

    // ================= stage 2: h2 = gelu(h1*W2+b2) + h1*Ws2+bs2 ==========
    {
        f32x4 acc1[4][3], acc2[4][3];
        #pragma unroll
        for (int i = 0; i < 4; i++)
            #pragma unroll
            for (int t = 0; t < 3; t++) { acc1[i][t] = (f32x4)0.f; acc2[i][t] = (f32x4)0.f; }
        const float* W2p  = W2  + (size_t)a * HDIM * HDIM;
        const float* Ws2p = Ws2 + (size_t)a * HDIM * HDIM;
        const float* wA[3] = { W2p + n0,  W2p + n0 + 16,  W2p + n0 + 32 };
        const float* wB[3] = { Ws2p + n0, Ws2p + n0 + 16, Ws2p + n0 + 32 };
        gemm_bpass<6, HDIM, 3, HDIM>(acc1, wA, As, lane);
        gemm_bpass<6, HDIM, 3, HDIM>(acc2, wB, As, lane);
        __syncthreads();
        #pragma unroll
        for (int t = 0; t < 3; t++) {
            int col = n0 + 16 * t + r;
            float bb  = b2[a * HDIM + col];
            float bbs = bs2[a * HDIM + col];
            #pragma unroll
            for (int rg = 0; rg < 4; rg++)
                #pragma unroll
                for (int i = 0; i < 4; i++) {
                    int row = 16 * rg + 4 * g + i;
                    float v = gelu_exact(acc1[rg][t][i] + bb) + acc2[rg][t][i] + bbs;
                    As[row * PA + col] = (__bf16)v;
                }
        }
        __syncthreads();
    }

    // ================= stage 3: t = h2 + h2*W3 + b3, then LN ==============
    {
        f32x4 acc[4][3];
        #pragma unroll
        for (int i = 0; i < 4; i++)
            #pragma unroll
            for (int t = 0; t < 3; t++) acc[i][t] = (f32x4)0.f;
        const float* W3p = W3 + (size_t)a * HDIM * HDIM;
        const float* wA[3] = { W3p + n0, W3p + n0 + 16, W3p + n0 + 32 };
        gemm_bpass<6, HDIM, 3, HDIM>(acc, wA, As, lane);
        __syncthreads();   // all MFMA reads of h2 done before overwrite
        #pragma unroll
        for (int t = 0; t < 3; t++) {
            int col = n0 + 16 * t + r;
            float bb = b3[a * HDIM + col];
            #pragma unroll
            for (int rg = 0; rg < 4; rg++)
                #pragma unroll
                for (int i = 0; i < 4; i++) {
                    int row = 16 * rg + 4 * g + i;
                    float v = (float)As[row * PA + col] + acc[rg][t][i] + bb;
                    As[row * PA + col] = (__bf16)v;
                }
        }
        __syncthreads();
    }

    // ---- hidden LN (per-agent affine) -> h3out (fp32) ----
    {
        int rr = tid >> 2, l = tid & 3;
        float s = 0.f, ss = 0.f;
        for (int k = l; k < HDIM; k += 4) { float v = (float)As[rr * PA + k]; s += v; ss += v * v; }
        s  += __shfl_down(s, 2, 4);  s  += __shfl_down(s, 1, 4);
        ss += __shfl_down(ss, 2, 4); ss += __shfl_down(ss, 1, 4);
        if (l == 0) {
            float mu = s * (1.0f / HDIM);
            float var = ss * (1.0f / HDIM) - mu * mu;
            mu_s[rr] = mu;
            rs_s[rr] = rsqrtf(var + LN_EPS);
        }
    }
    __syncthreads();
    for (int sidx = tid; sidx < 64 * HDIM; sidx += 256) {
        int rr = sidx / HDIM, c = sidx - rr * HDIM;
        float v = ((float)As[rr * PA + c] - mu_s[rr]) * rs_s[rr] * ln_h_g[a * HDIM + c] + ln_h_b[a * HDIM + c];
        h3out[((size_t)a * BATCH + rr) * HDIM + c] = v;
    }
}

// ---------------------------------------------------------------------------
// Kernel B: y = LN(h3, shared affine); fused Q|K|V GEMM on MFMA.
// One block per agent; wave w owns cols [48w,48w+48) of the 384-wide concat
// per pass (2 passes).  No barriers after LN setup.
// ---------------------------------------------------------------------------
__global__ __launch_bounds__(256, 2) void qkv_kernel(
    const float* __restrict__ h3,
    const float* __restrict__ aln_g, const float* __restrict__ aln_b,
    const float* __restrict__ Wq, const float* __restrict__ bq,
    const float* __restrict__ Wk, const float* __restrict__ bk,
    const float* __restrict__ Wv, const float* __restrict__ bv,
    float* __restrict__ qT, float* __restrict__ kT, float* __restrict__ vT)
{
    const int a    = blockIdx.x;
    const int tid  = threadIdx.x;
    const int wave = tid >> 6, lane = tid & 63;
    const int r = lane & 15, g = lane >> 4;

    __shared__ __align__(16) __bf16 ys[64 * PA];
    __shared__ float mu_s[64], rs_s[64];

    {
        int rr = tid >> 2, l = tid & 3;
        const float* hp = h3 + ((size_t)a * BATCH + rr) * HDIM;
        float s = 0.f, ss = 0.f;
        for (int k = l; k < HDIM; k += 4) { float v = hp[k]; s += v; ss += v * v; }
        s  += __shfl_down(s, 2, 4);  s  += __shfl_down(s, 1, 4);
        ss += __shfl_down(ss, 2, 4); ss += __shfl_down(ss, 1, 4);
        if (l == 0) {
            float mu = s * (1.0f / HDIM);
            float var = ss * (1.0f / HDIM) - mu * mu;
            mu_s[rr] = mu;
            rs_s[rr] = rsqrtf(var + LN_EPS);
        }
    }
    __syncthreads();
    for (int sidx = tid; sidx < 64 * HDIM; sidx += 256) {
        int rr = sidx / HDIM, c = sidx - rr * HDIM;
        float v = (h3[((size_t)a * BATCH + rr) * HDIM + c] - mu_s[rr]) * rs_s[rr] * aln_g[c] + aln_b[c];
        ys[rr * PA + c] = (__bf16)v;
    }
    __syncthreads();

    #pragma unroll
    for (int p = 0; p < 2; p++) {
        const int nb = 192 * p + 48 * wave;
        const float* wA[3];
        #pragma unroll
        for (int t = 0; t < 3; t++) {
            int nt = nb + 16 * t;
            const float* base = (nt < 128) ? Wq : (nt < 256) ? Wk : Wv;
            wA[t] = base + (nt & 127);
        }
        f32x4 acc[4][3];
        #pragma unroll
        for (int i = 0; i < 4; i++)
            #pragma unroll
            for (int t = 0; t < 3; t++) acc[i][t] = (f32x4)0.f;
        gemm_bpass<6, HDIM, 3, ADIMM>(acc, wA, ys, lane);

        #pragma unroll
        for (int t = 0; t < 3; t++) {
            int n = nb + 16 * t + r;
            int which = n >> 7, cc = n & 127, hh = cc >> 4, dd = cc & 15;
            const float* bp = (which == 0) ? bq : (which == 1) ? bk : bv;
            float* op = (which == 0) ? qT : (which == 1) ? kT : vT;
            float bb = bp[cc];
            #pragma unroll
            for (int rg = 0; rg < 4; rg++)
                #pragma unroll
                for (int i = 0; i < 4; i++) {
                    int brow = 16 * rg + 4 * g + i;
                    op[(((size_t)brow * NHEADS + hh) * AGENTS + a) * HEADD + dd] = acc[rg][t][i] + bb;
                }
        }
    }
}

// ---------------------------------------------------------------------------
// Kernel C: cross-agent attention.  grid = 512 (b,h); block 512 (8 waves).
// ---------------------------------------------------------------------------
__global__ __launch_bounds__(512) void attn_kernel(
    const float* __restrict__ qT, const float* __restrict__ kT,
    const float* __restrict__ vT, float* __restrict__ oT)
{
    const int bh  = blockIdx.x;
    const int tid = threadIdx.x;

    __shared__ float ks[AGENTS * HEADD];
    __shared__ float vs[AGENTS * HEADD];
    const float4* kp = (const float4*)(kT + (size_t)bh * AGENTS * HEADD);
    const float4* vp = (const float4*)(vT + (size_t)bh * AGENTS * HEADD);
    for (int i = tid; i < AGENTS * HEADD / 4; i += 512) {
        ((float4*)ks)[i] = kp[i];
        ((float4*)vs)[i] = vp[i];
    }
    __syncthreads();

    if (tid < AGENTS) {
        float q[16];
        const float* qp = qT + ((size_t)bh * AGENTS + tid) * HEADD;
        #pragma unroll
        for (int d = 0; d < 16; d++) q[d] = qp[d];

        float m = -1e30f, l = 0.f;
        float o[16];
        #pragma unroll
        for (int d = 0; d < 16; d++) o[d] = 0.f;

        for (int c = 0; c < AGENTS; c++) {
            const float* kk = &ks[c * HEADD];
            float s = 0.f;
            #pragma unroll
            for (int d = 0; d < 16; d++) s = fmaf(q[d], kk[d], s);
            s *= 0.25f;
            if (s > m) {
                float corr = __expf(m - s);
                l *= corr;
                #pragma unroll
                for (int d = 0; d < 16; d++) o[d] *= corr;
                m = s;
            }
            float p = __expf(s - m);
            l += p;
            const float* vv = &vs[c * HEADD];
            #pragma unroll
            for (int d = 0; d < 16; d++) o[d] = fmaf(p, vv[d], o[d]);
        }
        float inv = 1.0f / l;
        float* op = oT + ((size_t)bh * AGENTS + tid) * HEADD;
        #pragma unroll
        for (int d = 0; d < 16; d++) op[d] = o[d] * inv;
    }
}

// ---------------------------------------------------------------------------
// Kernel D: attended = h3 + o*Wo + bo; logits = attended*Wout[a] + bout[a].
// ---------------------------------------------------------------------------
__global__ __launch_bounds__(256) void out_kernel(
    const float* __restrict__ h3, const float* __restrict__ oT,
    const float* __restrict__ Wo, const float* __restrict__ bo,
    const float* __restrict__ Wout, const float* __restrict__ bout,
    float* __restrict__ out)
{
    const int a      = blockIdx.x;
    const int r_base = blockIdx.y * 32;
    const int tid    = threadIdx.x;
    __shared__ float os[32][ADIMM + 1];
    __shared__ float att[32][HDIM + 1];

    for (int idx = tid; idx < 32 * HDIM; idx += 256) {
        int rr = idx / HDIM, c = idx - rr * HDIM;
        att[rr][c] = h3[((size_t)a * BATCH + (r_base + rr)) * HDIM + c];
    }
    for (int idx = tid; idx < 32 * ADIMM; idx += 256) {
        int rr = idx >> 7, j = idx & 127;
        int h = j >> 4, d = j & 15;
        int b = r_base + rr;
        os[rr][j] = oT[(((size_t)b * NHEADS + h) * AGENTS + a) * HEADD + d];
    }
    __syncthreads();

    const int cx = tid & 63;
    const int rg = (tid >> 6) * 8;
    {
        float acc[3][8];
        #pragma unroll
        for (int m = 0; m < 3; m++)
            #pragma unroll
            for (int rr = 0; rr < 8; rr++) acc[m][rr] = 0.f;
        for (int k = 0; k < ADIMM; k++) {
            float w[3];
            #pragma unroll
            for (int m = 0; m < 3; m++) w[m] = Wo[k * HDIM + cx + 64 * m];
            #pragma unroll
            for (int rr = 0; rr < 8; rr++) {
                float ov = os[rg + rr][k];
                #pragma unroll
                for (int m = 0; m < 3; m++) acc[m][rr] = fmaf(ov, w[m], acc[m][rr]);
            }
        }
        #pragma unroll
        for (int m = 0; m < 3; m++) {
            int c = cx + 64 * m;
            float bb = bo[c];
            #pragma unroll
            for (int rr = 0; rr < 8; rr++)
                att[rg + rr][c] += acc[m][rr] + bb;
        }
    }
    __syncthreads();

    if (tid < 32 * ODIM) {
        int rr = tid & 31;
        int c = tid >> 5;
        const float* Wp = Wout + (size_t)a * HDIM * ODIM;
        float accv = 0.f;
        for (int k = 0; k < HDIM; k++)
            accv = fmaf(att[rr][k], Wp[k * ODIM + c], accv);
        out[((size_t)a * BATCH + (r_base + rr)) * ODIM + c] = accv + bout[a * ODIM + c];
    }
}

// ---------------------------------------------------------------------------
extern "C" void kernel_launch(void* const* d_in, const int* in_sizes, int n_in,
                              void* d_out, int out_size, void* d_ws, size_t ws_size,
                              hipStream_t stream)
{
    const float* x       = (const float*)d_in[0];
    const float* ln_in_g = (const float*)d_in[1];
    const float* ln_in_b = (const float*)d_in[2];
    const float* W1      = (const float*)d_in[3];
    const float* b1      = (const float*)d_in[4];
    const float* Ws1     = (const float*)d_in[5];
    const float* bs1     = (const float*)d_in[6];
    const float* W2      = (const float*)d_in[7];
    const float* b2      = (const float*)d_in[8];
    const float* Ws2     = (const float*)d_in[9];
    const float* bs2     = (const float*)d_in[10];
    const float* W3      = (const float*)d_in[11];
    const float* b3      = (const float*)d_in[12];
    const float* ln_h_g  = (const float*)d_in[13];
    const float* ln_h_b  = (const float*)d_in[14];
    const float* Wout    = (const float*)d_in[15];
    const float* bout    = (const float*)d_in[16];
    const float* aln_g   = (const float*)d_in[17];
    const float* aln_b   = (const float*)d_in[18];
    const float* Wq      = (const float*)d_in[19];
    const float* bq      = (const float*)d_in[20];
    const float* Wk      = (const float*)d_in[21];
    const float* bk      = (const float*)d_in[22];
    const float* Wv      = (const float*)d_in[23];
    const float* bv      = (const float*)d_in[24];
    const float* Wo      = (const float*)d_in[25];
    const float* bo      = (const float*)d_in[26];
    float* out = (float*)d_out;

    float* ws = (float*)d_ws;
    const size_t H3_SZ = (size_t)AGENTS * BATCH * HDIM;
    const size_t QT_SZ = (size_t)BATCH * NHEADS * AGENTS * HEADD;
    float* h3 = ws;
    float* qT = h3 + H3_SZ;
    float* kT = qT + QT_SZ;
    float* vT = kT + QT_SZ;
    float* oT = vT + QT_SZ;

    mlp_kernel<<<AGENTS, 256, 0, stream>>>(x, ln_in_g, ln_in_b,
                                           W1, b1, Ws1, bs1, W2, b2, Ws2, bs2,
                                           W3, b3, ln_h_g, ln_h_b, h3);
    qkv_kernel<<<AGENTS, 256, 0, stream>>>(h3, aln_g, aln_b,
                                           Wq, bq, Wk, bk, Wv, bv, qT, kT, vT);
    attn_kernel<<<BATCH * NHEADS, 512, 0, stream>>>(qT, kT, vT, oT);
    out_kernel<<<dim3(AGENTS, 2), 256, 0, stream>>>(h3, oT, Wo, bo, Wout, bout, out);
}

// Round 5
// 400.670 us; speedup vs baseline: 2.4434x; 1.2128x over previous
//
#include <hip/hip_runtime.h>
#include <math.h>

#define AGENTS 400
#define BATCH  64
#define IDIM   50
#define HDIM   192
#define ODIM   3
#define ADIMM  128
#define NHEADS 8
#define HEADD  16
#define LN_EPS 1e-5f

#define PA 200   // activation LDS pitch in bf16 (400 B rows, 16B-aligned)

typedef __bf16 bf16x8 __attribute__((ext_vector_type(8)));
typedef float  f32x4  __attribute__((ext_vector_type(4)));

__device__ __forceinline__ float gelu_exact(float x) {
    return 0.5f * x * (1.0f + erff(x * 0.70710678118654752f));
}

// ---------------------------------------------------------------------------
// Barrier-free GEMM pass over K (NC chunks of 32), B built straight from
// global fp32 into register fragments, double-buffered one chunk ahead.
// ---------------------------------------------------------------------------
template<int NC, int KD, int NT, int LDW>
__device__ __forceinline__ void gemm_bpass(f32x4 (&acc)[4][NT],
                                           const float* const* wptr,
                                           const __bf16* Asrc, int lane)
{
    const int r = lane & 15, g = lane >> 4;
    float buf[2][NT * 8];

    #pragma unroll
    for (int t = 0; t < NT; t++)
        #pragma unroll
        for (int j = 0; j < 8; j++) {
            int k = g * 8 + j;
            buf[0][t * 8 + j] = (k < KD) ? wptr[t][k * LDW + r] : 0.f;
        }

    #pragma unroll
    for (int c = 0; c < NC; c++) {
        const int cur = c & 1, nxt = cur ^ 1;
        if (c + 1 < NC) {
            #pragma unroll
            for (int t = 0; t < NT; t++)
                #pragma unroll
                for (int j = 0; j < 8; j++) {
                    int k = (c + 1) * 32 + g * 8 + j;
                    buf[nxt][t * 8 + j] = (k < KD) ? wptr[t][k * LDW + r] : 0.f;
                }
        }
        bf16x8 bfr[NT];
        #pragma unroll
        for (int t = 0; t < NT; t++)
            #pragma unroll
            for (int j = 0; j < 8; j++)
                bfr[t][j] = (__bf16)buf[cur][t * 8 + j];
        #pragma unroll
        for (int rg = 0; rg < 4; rg++) {
            bf16x8 af = *(const bf16x8*)&Asrc[(16 * rg + r) * PA + c * 32 + g * 8];
            #pragma unroll
            for (int t = 0; t < NT; t++)
                acc[rg][t] = __builtin_amdgcn_mfma_f32_16x16x32_bf16(af, bfr[t], acc[rg][t], 0, 0, 0);
        }
    }
}

// ---------------------------------------------------------------------------
// Kernel A: per-agent MLP on MFMA.  One block (4 waves) per agent.
// ---------------------------------------------------------------------------
__global__ __launch_bounds__(256, 2) void mlp_kernel(
    const float* __restrict__ x,
    const float* __restrict__ ln_in_g, const float* __restrict__ ln_in_b,
    const float* __restrict__ W1, const float* __restrict__ b1,
    const float* __restrict__ Ws1, const float* __restrict__ bs1,
    const float* __restrict__ W2, const float* __restrict__ b2,
    const float* __restrict__ Ws2, const float* __restrict__ bs2,
    const float* __restrict__ W3, const float* __restrict__ b3,
    const float* __restrict__ ln_h_g, const float* __restrict__ ln_h_b,
    float* __restrict__ h3out)
{
    const int a    = blockIdx.x;
    const int tid  = threadIdx.x;
    const int wave = tid >> 6, lane = tid & 63;
    const int r = lane & 15, g = lane >> 4;
    const int n0 = 48 * wave;

    __shared__ __align__(16) __bf16 As[64 * PA];   // 25.6 KB
    __shared__ float mu_s[64], rs_s[64];

    {
        int rr = tid >> 2, l = tid & 3;
        float s = 0.f, ss = 0.f;
        for (int k = l; k < IDIM; k += 4) { float v = x[rr * IDIM + k]; s += v; ss += v * v; }
        s  += __shfl_down(s, 2, 4);  s  += __shfl_down(s, 1, 4);
        ss += __shfl_down(ss, 2, 4); ss += __shfl_down(ss, 1, 4);
        if (l == 0) {
            float mu = s * (1.0f / IDIM);
            float var = ss * (1.0f / IDIM) - mu * mu;
            mu_s[rr] = mu;
            rs_s[rr] = rsqrtf(var + LN_EPS);
        }
    }
    __syncthreads();
    for (int sidx = tid; sidx < 64 * 64; sidx += 256) {
        int rr = sidx >> 6, k = sidx & 63;
        float v = 0.f;
        if (k < IDIM)
            v = (x[rr * IDIM + k] - mu_s[rr]) * rs_s[rr] * ln_in_g[a * IDIM + k] + ln_in_b[a * IDIM + k];
        As[rr * PA + k] = (__bf16)v;
    }
    __syncthreads();

    // stage 1
    {
        f32x4 acc1[4][3], acc2[4][3];
        #pragma unroll
        for (int i = 0; i < 4; i++)
            #pragma unroll
            for (int t = 0; t < 3; t++) { acc1[i][t] = (f32x4)0.f; acc2[i][t] = (f32x4)0.f; }
        const float* W1p  = W1  + (size_t)a * IDIM * HDIM;
        const float* Ws1p = Ws1 + (size_t)a * IDIM * HDIM;
        const float* wA[3] = { W1p + n0,  W1p + n0 + 16,  W1p + n0 + 32 };
        const float* wB[3] = { Ws1p + n0, Ws1p + n0 + 16, Ws1p + n0 + 32 };
        gemm_bpass<2, IDIM, 3, HDIM>(acc1, wA, As, lane);
        gemm_bpass<2, IDIM, 3, HDIM>(acc2, wB, As, lane);
        __syncthreads();
        #pragma unroll
        for (int t = 0; t < 3; t++) {
            int col = n0 + 16 * t + r;
            float bb  = b1[a * HDIM + col];
            float bbs = bs1[a * HDIM + col];
            #pragma unroll
            for (int rg = 0; rg < 4; rg++)
                #pragma unroll
                for (int i = 0; i < 4; i++) {
                    int row = 16 * rg + 4 * g + i;
                    float v = gelu_exact(acc1[rg][t][i] + bb) + acc2[rg][t][i] + bbs;
                    As[row * PA + col] = (__bf16)v;
                }
        }
        __syncthreads();
    }

    // stage 2
    {
        f32x4 acc1[4][3], acc2[4][3];
        #pragma unroll
        for (int i = 0; i < 4; i++)
            #pragma unroll
            for (int t = 0; t < 3; t++) { acc1[i][t] = (f32x4)0.f; acc2[i][t] = (f32x4)0.f; }
        const float* W2p  = W2  + (size_t)a * HDIM * HDIM;
        const float* Ws2p = Ws2 + (size_t)a * HDIM * HDIM;
        const float* wA[3] = { W2p + n0,  W2p + n0 + 16,  W2p + n0 + 32 };
        const float* wB[3] = { Ws2p + n0, Ws2p + n0 + 16, Ws2p + n0 + 32 };
        gemm_bpass<6, HDIM, 3, HDIM>(acc1, wA, As, lane);
        gemm_bpass<6, HDIM, 3, HDIM>(acc2, wB, As, lane);
        __syncthreads();
        #pragma unroll
        for (int t = 0; t < 3; t++) {
            int col = n0 + 16 * t + r;
            float bb  = b2[a * HDIM + col];
            float bbs = bs2[a * HDIM + col];
            #pragma unroll
            for (int rg = 0; rg < 4; rg++)
                #pragma unroll
                for (int i = 0; i < 4; i++) {
                    int row = 16 * rg + 4 * g + i;
                    float v = gelu_exact(acc1[rg][t][i] + bb) + acc2[rg][t][i] + bbs;
                    As[row * PA + col] = (__bf16)v;
                }
        }
        __syncthreads();
    }

    // stage 3 + LN
    {
        f32x4 acc[4][3];
        #pragma unroll
        for (int i = 0; i < 4; i++)
            #pragma unroll
            for (int t = 0; t < 3; t++) acc[i][t] = (f32x4)0.f;
        const float* W3p = W3 + (size_t)a * HDIM * HDIM;
        const float* wA[3] = { W3p + n0, W3p + n0 + 16, W3p + n0 + 32 };
        gemm_bpass<6, HDIM, 3, HDIM>(acc, wA, As, lane);
        __syncthreads();
        #pragma unroll
        for (int t = 0; t < 3; t++) {
            int col = n0 + 16 * t + r;
            float bb = b3[a * HDIM + col];
            #pragma unroll
            for (int rg = 0; rg < 4; rg++)
                #pragma unroll
                for (int i = 0; i < 4; i++) {
                    int row = 16 * rg + 4 * g + i;
                    float v = (float)As[row * PA + col] + acc[rg][t][i] + bb;
                    As[row * PA + col] = (__bf16)v;
                }
        }
        __syncthreads();
    }

    {
        int rr = tid >> 2, l = tid & 3;
        float s = 0.f, ss = 0.f;
        for (int k = l; k < HDIM; k += 4) { float v = (float)As[rr * PA + k]; s += v; ss += v * v; }
        s  += __shfl_down(s, 2, 4);  s  += __shfl_down(s, 1, 4);
        ss += __shfl_down(ss, 2, 4); ss += __shfl_down(ss, 1, 4);
        if (l == 0) {
            float mu = s * (1.0f / HDIM);
            float var = ss * (1.0f / HDIM) - mu * mu;
            mu_s[rr] = mu;
            rs_s[rr] = rsqrtf(var + LN_EPS);
        }
    }
    __syncthreads();
    for (int sidx = tid; sidx < 64 * HDIM; sidx += 256) {
        int rr = sidx / HDIM, c = sidx - rr * HDIM;
        float v = ((float)As[rr * PA + c] - mu_s[rr]) * rs_s[rr] * ln_h_g[a * HDIM + c] + ln_h_b[a * HDIM + c];
        h3out[((size_t)a * BATCH + rr) * HDIM + c] = v;
    }
}

// ---------------------------------------------------------------------------
// Kernel B: y = LN(h3, shared affine); fused Q|K|V GEMM on MFMA.
// ---------------------------------------------------------------------------
__global__ __launch_bounds__(256, 2) void qkv_kernel(
    const float* __restrict__ h3,
    const float* __restrict__ aln_g, const float* __restrict__ aln_b,
    const float* __restrict__ Wq, const float* __restrict__ bq,
    const float* __restrict__ Wk, const float* __restrict__ bk,
    const float* __restrict__ Wv, const float* __restrict__ bv,
    float* __restrict__ qT, float* __restrict__ kT, float* __restrict__ vT)
{
    const int a    = blockIdx.x;
    const int tid  = threadIdx.x;
    const int wave = tid >> 6, lane = tid & 63;
    const int r = lane & 15, g = lane >> 4;

    __shared__ __align__(16) __bf16 ys[64 * PA];
    __shared__ float mu_s[64], rs_s[64];

    {
        int rr = tid >> 2, l = tid & 3;
        const float* hp = h3 + ((size_t)a * BATCH + rr) * HDIM;
        float s = 0.f, ss = 0.f;
        for (int k = l; k < HDIM; k += 4) { float v = hp[k]; s += v; ss += v * v; }
        s  += __shfl_down(s, 2, 4);  s  += __shfl_down(s, 1, 4);
        ss += __shfl_down(ss, 2, 4); ss += __shfl_down(ss, 1, 4);
        if (l == 0) {
            float mu = s * (1.0f / HDIM);
            float var = ss * (1.0f / HDIM) - mu * mu;
            mu_s[rr] = mu;
            rs_s[rr] = rsqrtf(var + LN_EPS);
        }
    }
    __syncthreads();
    for (int sidx = tid; sidx < 64 * HDIM; sidx += 256) {
        int rr = sidx / HDIM, c = sidx - rr * HDIM;
        float v = (h3[((size_t)a * BATCH + rr) * HDIM + c] - mu_s[rr]) * rs_s[rr] * aln_g[c] + aln_b[c];
        ys[rr * PA + c] = (__bf16)v;
    }
    __syncthreads();

    #pragma unroll
    for (int p = 0; p < 2; p++) {
        const int nb = 192 * p + 48 * wave;
        const float* wA[3];
        #pragma unroll
        for (int t = 0; t < 3; t++) {
            int nt = nb + 16 * t;
            const float* base = (nt < 128) ? Wq : (nt < 256) ? Wk : Wv;
            wA[t] = base + (nt & 127);
        }
        f32x4 acc[4][3];
        #pragma unroll
        for (int i = 0; i < 4; i++)
            #pragma unroll
            for (int t = 0; t < 3; t++) acc[i][t] = (f32x4)0.f;
        gemm_bpass<6, HDIM, 3, ADIMM>(acc, wA, ys, lane);

        #pragma unroll
        for (int t = 0; t < 3; t++) {
            int n = nb + 16 * t + r;
            int which = n >> 7, cc = n & 127, hh = cc >> 4, dd = cc & 15;
            const float* bp = (which == 0) ? bq : (which == 1) ? bk : bv;
            float* op = (which == 0) ? qT : (which == 1) ? kT : vT;
            float bb = bp[cc];
            #pragma unroll
            for (int rg = 0; rg < 4; rg++)
                #pragma unroll
                for (int i = 0; i < 4; i++) {
                    int brow = 16 * rg + 4 * g + i;
                    op[(((size_t)brow * NHEADS + hh) * AGENTS + a) * HEADD + dd] = acc[rg][t][i] + bb;
                }
        }
    }
}

// ---------------------------------------------------------------------------
// Kernel C: cross-agent attention on MFMA.  One block (4 waves) per (b,h);
// grid = 512 = exactly 2 blocks/CU (LDS 60.5 KB).
// Per wave, per 16-row Q-tile: S = Q.K^T (25 MFMAs, d zero-padded via zero
// A-regs on lanes g>=2), two-pass softmax in C-layout regs, P -> per-wave LDS
// buffer in two halves (208+192 agents), PV (7+6 MFMAs) vs V^T in LDS.
// No __syncthreads in the tile loop (waves have unequal trip counts);
// wave-internal DS ordering + explicit lgkmcnt(0) instead.
// ---------------------------------------------------------------------------
#define PKA 24    // Ks pitch in bf16 (48 B rows: 16B-aligned, 2-way banks)
#define PVA 408   // Vt pitch in bf16 (816 B rows: 16B-aligned, 2-way banks)
#define PPA 232   // Ps pitch in bf16 (464 B rows: 16B-aligned, 2-way banks)

__global__ __launch_bounds__(256, 2) void attn_kernel(
    const float* __restrict__ qT, const float* __restrict__ kT,
    const float* __restrict__ vT, float* __restrict__ oT)
{
    const int bh   = blockIdx.x;
    const int tid  = threadIdx.x;
    const int wave = tid >> 6, lane = tid & 63;
    const int r = lane & 15, g = lane >> 4;

    __shared__ __align__(16) __bf16 Ks[AGENTS * PKA];      // 19.2 KB
    __shared__ __align__(16) __bf16 Vt[16 * PVA];          // 13.1 KB
    __shared__ __align__(16) __bf16 Ps[4][16 * PPA];       // 29.7 KB

    const float* kp = kT + (size_t)bh * AGENTS * HEADD;
    const float* vp = vT + (size_t)bh * AGENTS * HEADD;
    for (int idx = tid; idx < AGENTS * HEADD; idx += 256) {
        int a_ = idx >> 4, d = idx & 15;
        Ks[a_ * PKA + d] = (__bf16)kp[idx];
        Vt[d * PVA + a_] = (__bf16)vp[idx];
    }
    __bf16* Pw = Ps[wave];
    // zero P cols [208,224) once: half-0 PV reads them as padding
    for (int z = lane; z < 16 * 16; z += 64)
        Pw[(z >> 4) * PPA + 208 + (z & 15)] = (__bf16)0.f;
    __syncthreads();

    for (int mt = wave; mt < 25; mt += 4) {
        const int m0 = mt * 16;

        // Q A-frag from global (x SCALE); k>=16 lanes hold zeros
        bf16x8 aq;
        if (g < 2) {
            const float* qp = qT + ((size_t)bh * AGENTS + m0 + r) * HEADD + g * 8;
            #pragma unroll
            for (int j = 0; j < 8; j++) aq[j] = (__bf16)(qp[j] * 0.25f);
        } else {
            #pragma unroll
            for (int j = 0; j < 8; j++) aq[j] = (__bf16)0.f;
        }

        // S = Q.K^T : 25 col-tiles.  B content for g>=2 is irrelevant (A=0).
        f32x4 sacc[25];
        #pragma unroll
        for (int t = 0; t < 25; t++) {
            bf16x8 bk_ = *(const bf16x8*)&Ks[(t * 16 + r) * PKA + (g & 1) * 8];
            sacc[t] = __builtin_amdgcn_mfma_f32_16x16x32_bf16(aq, bk_, (f32x4)0.f, 0, 0, 0);
        }

        // two-pass softmax: lane holds rows g*4+i, col t*16+r
        float lv[4];
        #pragma unroll
        for (int i = 0; i < 4; i++) {
            float m_ = sacc[0][i];
            #pragma unroll
            for (int t = 1; t < 25; t++) m_ = fmaxf(m_, sacc[t][i]);
            #pragma unroll
            for (int off = 8; off; off >>= 1) m_ = fmaxf(m_, __shfl_xor(m_, off, 16));
            float l_ = 0.f;
            #pragma unroll
            for (int t = 0; t < 25; t++) {
                float p = __expf(sacc[t][i] - m_);
                sacc[t][i] = p;
                l_ += p;
            }
            #pragma unroll
            for (int off = 8; off; off >>= 1) l_ += __shfl_xor(l_, off, 16);
            lv[i] = l_;
        }

        f32x4 oacc = (f32x4)0.f;

        // ---- half 0: agents [0,208) as P cols 0..207 (+ zeros 208..223) ----
        #pragma unroll
        for (int t = 0; t < 13; t++)
            #pragma unroll
            for (int i = 0; i < 4; i++)
                Pw[(g * 4 + i) * PPA + t * 16 + r] = (__bf16)sacc[t][i];
        __asm__ volatile("s_waitcnt lgkmcnt(0)" ::: "memory");
        #pragma unroll
        for (int c = 0; c < 7; c++) {
            bf16x8 ap  = *(const bf16x8*)&Pw[r * PPA + c * 32 + g * 8];
            bf16x8 bv_ = *(const bf16x8*)&Vt[r * PVA + c * 32 + g * 8];
            oacc = __builtin_amdgcn_mfma_f32_16x16x32_bf16(ap, bv_, oacc, 0, 0, 0);
        }

        // ---- half 1: agents [208,400) as P cols 0..191 (zero 192..207) ----
        for (int z = lane; z < 16 * 16; z += 64)
            Pw[(z >> 4) * PPA + 192 + (z & 15)] = (__bf16)0.f;
        #pragma unroll
        for (int t = 13; t < 25; t++)
            #pragma unroll
            for (int i = 0; i < 4; i++)
                Pw[(g * 4 + i) * PPA + (t - 13) * 16 + r] = (__bf16)sacc[t][i];
        __asm__ volatile("s_waitcnt lgkmcnt(0)" ::: "memory");
        #pragma unroll
        for (int c = 0; c < 6; c++) {
            bf16x8 ap  = *(const bf16x8*)&Pw[r * PPA + c * 32 + g * 8];
            bf16x8 bv_ = *(const bf16x8*)&Vt[r * PVA + 208 + c * 32 + g * 8];
            oacc = __builtin_amdgcn_mfma_f32_16x16x32_bf16(ap, bv_, oacc, 0, 0, 0);
        }

        // O tile: col=lane&15 -> d, row=g*4+i; normalize by 1/l
        float* op = oT + ((size_t)bh * AGENTS + m0) * HEADD;
        #pragma unroll
        for (int i = 0; i < 4; i++)
            op[(g * 4 + i) * HEADD + r] = oacc[i] / lv[i];
    }
}

// ---------------------------------------------------------------------------
// Kernel D: attended = h3 + o*Wo + bo; logits = attended*Wout[a] + bout[a].
// ---------------------------------------------------------------------------
__global__ __launch_bounds__(256) void out_kernel(
    const float* __restrict__ h3, const float* __restrict__ oT,
    const float* __restrict__ Wo, const float* __restrict__ bo,
    const float* __restrict__ Wout, const float* __restrict__ bout,
    float* __restrict__ out)
{
    const int a      = blockIdx.x;
    const int r_base = blockIdx.y * 32;
    const int tid    = threadIdx.x;
    __shared__ float os[32][ADIMM + 1];
    __shared__ float att[32][HDIM + 1];

    for (int idx = tid; idx < 32 * HDIM; idx += 256) {
        int rr = idx / HDIM, c = idx - rr * HDIM;
        att[rr][c] = h3[((size_t)a * BATCH + (r_base + rr)) * HDIM + c];
    }
    for (int idx = tid; idx < 32 * ADIMM; idx += 256) {
        int rr = idx >> 7, j = idx & 127;
        int h = j >> 4, d = j & 15;
        int b = r_base + rr;
        os[rr][j] = oT[(((size_t)b * NHEADS + h) * AGENTS + a) * HEADD + d];
    }
    __syncthreads();

    const int cx = tid & 63;
    const int rg = (tid >> 6) * 8;
    {
        float acc[3][8];
        #pragma unroll
        for (int m = 0; m < 3; m++)
            #pragma unroll
            for (int rr = 0; rr < 8; rr++) acc[m][rr] = 0.f;
        for (int k = 0; k < ADIMM; k++) {
            float w[3];
            #pragma unroll
            for (int m = 0; m < 3; m++) w[m] = Wo[k * HDIM + cx + 64 * m];
            #pragma unroll
            for (int rr = 0; rr < 8; rr++) {
                float ov = os[rg + rr][k];
                #pragma unroll
                for (int m = 0; m < 3; m++) acc[m][rr] = fmaf(ov, w[m], acc[m][rr]);
            }
        }
        #pragma unroll
        for (int m = 0; m < 3; m++) {
            int c = cx + 64 * m;
            float bb = bo[c];
            #pragma unroll
            for (int rr = 0; rr < 8; rr++)
                att[rg + rr][c] += acc[m][rr] + bb;
        }
    }
    __syncthreads();

    if (tid < 32 * ODIM) {
        int rr = tid & 31;
        int c = tid >> 5;
        const float* Wp = Wout + (size_t)a * HDIM * ODIM;
        float accv = 0.f;
        for (int k = 0; k < HDIM; k++)
            accv = fmaf(att[rr][k], Wp[k * ODIM + c], accv);
        out[((size_t)a * BATCH + (r_base + rr)) * ODIM + c] = accv + bout[a * ODIM + c];
    }
}

// ---------------------------------------------------------------------------
extern "C" void kernel_launch(void* const* d_in, const int* in_sizes, int n_in,
                              void* d_out, int out_size, void* d_ws, size_t ws_size,
                              hipStream_t stream)
{
    const float* x       = (const float*)d_in[0];
    const float* ln_in_g = (const float*)d_in[1];
    const float* ln_in_b = (const float*)d_in[2];
    const float* W1      = (const float*)d_in[3];
    const float* b1      = (const float*)d_in[4];
    const float* Ws1     = (const float*)d_in[5];
    const float* bs1     = (const float*)d_in[6];
    const float* W2      = (const float*)d_in[7];
    const float* b2      = (const float*)d_in[8];
    const float* Ws2     = (const float*)d_in[9];
    const float* bs2     = (const float*)d_in[10];
    const float* W3      = (const float*)d_in[11];
    const float* b3      = (const float*)d_in[12];
    const float* ln_h_g  = (const float*)d_in[13];
    const float* ln_h_b  = (const float*)d_in[14];
    const float* Wout    = (const float*)d_in[15];
    const float* bout    = (const float*)d_in[16];
    const float* aln_g   = (const float*)d_in[17];
    const float* aln_b   = (const float*)d_in[18];
    const float* Wq      = (const float*)d_in[19];
    const float* bq      = (const float*)d_in[20];
    const float* Wk      = (const float*)d_in[21];
    const float* bk      = (const float*)d_in[22];
    const float* Wv      = (const float*)d_in[23];
    const float* bv      = (const float*)d_in[24];
    const float* Wo      = (const float*)d_in[25];
    const float* bo      = (const float*)d_in[26];
    float* out = (float*)d_out;

    float* ws = (float*)d_ws;
    const size_t H3_SZ = (size_t)AGENTS * BATCH * HDIM;
    const size_t QT_SZ = (size_t)BATCH * NHEADS * AGENTS * HEADD;
    float* h3 = ws;
    float* qT = h3 + H3_SZ;
    float* kT = qT + QT_SZ;
    float* vT = kT + QT_SZ;
    float* oT = vT + QT_SZ;

    mlp_kernel<<<AGENTS, 256, 0, stream>>>(x, ln_in_g, ln_in_b,
                                           W1, b1, Ws1, bs1, W2, b2, Ws2, bs2,
                                           W3, b3, ln_h_g, ln_h_b, h3);
    qkv_kernel<<<AGENTS, 256, 0, stream>>>(h3, aln_g, aln_b,
                                           Wq, bq, Wk, bk, Wv, bv, qT, kT, vT);
    attn_kernel<<<BATCH * NHEADS, 256, 0, stream>>>(qT, kT, vT, oT);
    out_kernel<<<dim3(AGENTS, 2), 256, 0, stream>>>(h3, oT, Wo, bo, Wout, bout, out);
}